// Round 1
// baseline (1138.343 us; speedup 1.0000x reference)
//
#include <hip/hip_runtime.h>
#include <math.h>

#define B 16
#define T 6000
#define H 256
#define NPOS 6001            // T+1 segments
#define NOTE_CLS 104
#define NOTE_NUM 100
#define NOTE_START 30
#define MIN_GAP 9
#define NSEG 1024            // cap on materialized segments (actual max len ~255)
#define TILE 32
#define NT ((NPOS + TILE - 1) / TILE)   // 188
#define XR 36                // agg rows per tile: [t0-2, t0+TILE+1]
#define YR 34                // y/u rows per tile: [t0-1, t0+TILE]
#define XSTR 40              // padded LDS row stride (16B-aligned)

// ---------------- Kernel 1: bd + attn dot products (f64 accumulate) ----------
__global__ __launch_bounds__(256) void k_dots(
    const float* __restrict__ feat,
    const float* __restrict__ w_bd, const float* __restrict__ b_bd,
    const float* __restrict__ w_attn, const float* __restrict__ b_attn,
    float* __restrict__ out_logits, double* __restrict__ dlog,
    float* __restrict__ amean)
{
  int lane = threadIdx.x & 63, wv = threadIdx.x >> 6;
  int row = blockIdx.x * 4 + wv;                      // b*T + t
  if (row >= B * T) return;
  float4 f  = ((const float4*)(feat + (size_t)row * H))[lane];
  float4 wb = ((const float4*)w_bd)[lane];
  float4 wa = ((const float4*)w_attn)[lane];
  double sb = (double)f.x * wb.x + (double)f.y * wb.y + (double)f.z * wb.z + (double)f.w * wb.w;
  double sa = (double)f.x * wa.x + (double)f.y * wa.y + (double)f.z * wa.z + (double)f.w * wa.w;
  for (int off = 32; off; off >>= 1) { sb += __shfl_down(sb, off); sa += __shfl_down(sa, off); }
  if (lane == 0) {
    double lb = sb + (double)b_bd[0];
    lb = fmin(fmax(lb, -16.0), 16.0);
    out_logits[row] = (float)lb;
    dlog[row] = lb;
    double la = sa + (double)b_attn[0];
    amean[row] = (float)(1.0 / (1.0 + exp(-la)));
  }
}

// ---------------- Kernel 2: regulate_boundary (sequential per row) -----------
__global__ __launch_bounds__(64) void k_regulate(
    const double* __restrict__ dlog, const int* __restrict__ non_padding,
    float* __restrict__ out_bd, float* __restrict__ out_len,
    int* __restrict__ seg_start, int* __restrict__ note_len)
{
  __shared__ int res_s[T];
  int b = blockIdx.x, lane = threadIdx.x;
  for (int t = lane; t < T; t += 64) res_s[t] = 0;
  __syncthreads();

  int start = -1, last = -1, best_i = 0;
  double best_v = -1e30;
  const double* row = dlog + (size_t)b * T;
  for (int t0 = 0; t0 < T; t0 += 64) {
    double d = (t0 + lane < T) ? row[t0 + lane] : -1e30;
    int jmax = (T - t0 < 64) ? (T - t0) : 64;
    #pragma unroll 1
    for (int j = 0; j < jmax; ++j) {
      int t = t0 + j;
      double pj = __shfl(d, j);
      bool is_one  = pj > 0.0;                         // sigmoid(x)>0.5 <=> x>0
      bool opening = is_one && (start < 0);
      bool upd = opening || (is_one && start >= 0 && pj > best_v);
      if (upd) { best_i = t; best_v = pj; }
      if (opening) start = t;
      bool close = (!is_one) && (start >= 0);
      if (close) {
        bool merge = ((best_i - last) < MIN_GAP) && (last > 0);
        int fi = best_i;
        if (merge) fi = (int)rint((double)(best_i + last) * 0.5);  // half-to-even
        if (lane == 0) {
          if (merge) res_s[last] = 0;
          res_s[fi] = 1;
        }
        last = fi; start = -1;
      }
    }
  }
  __syncthreads();

  // lens = sum(non_padding[b])
  int lens = 0;
  const int* npr = non_padding + (size_t)b * T;
  for (int t = lane; t < T; t += 64) lens += npr[t];
  for (int off = 32; off; off >>= 1) lens += __shfl_down(lens, off);
  lens = __shfl(lens, 0);

  if (lane == 0) res_s[0] = 0;
  int z0 = lens - 1; if (z0 < 0) z0 = 0;
  for (int t = z0 + lane; t < T; t += 64) res_s[t] = 0;
  __syncthreads();

  // compact boundary positions -> seg_start, write outputs
  int* ss = seg_start + b * (T + 2);
  if (lane == 0) ss[0] = 0;
  int cnt = 0;
  for (int t0 = 0; t0 < T; t0 += 64) {
    int t = t0 + lane;
    int bit = (t < T) ? res_s[t] : 0;
    unsigned long long mask = __ballot(bit);
    if (bit) {
      int rank = __popcll(mask & ((1ull << lane) - 1ull));
      ss[cnt + rank + 1] = t;
    }
    cnt += __popcll(mask);
    if (t < T) out_bd[(size_t)b * T + t] = (float)bit;
  }
  if (lane == 0) {
    ss[cnt + 1] = T;                   // sentinel end of last segment
    note_len[b] = cnt + 1;
    out_len[b] = (float)(cnt + 1);
  }
}

// ---------------- Kernel 3: constant tail logits (zero-agg positions) --------
__global__ __launch_bounds__(256) void k_consts(
    const float* __restrict__ conv_b, const float* __restrict__ ln_g,
    const float* __restrict__ ln_b, const float* __restrict__ post_w,
    const float* __restrict__ post_b, const float* __restrict__ w_pitch,
    const float* __restrict__ b_pitch,
    float* __restrict__ lmid, float* __restrict__ ledge, int* __restrict__ preds)
{
  __shared__ float hc[H], zm[H], ze[H], red[8];
  __shared__ float lm[NOTE_CLS], le[NOTE_CLS];
  int tid = threadIdx.x, lane = tid & 63, wv = tid >> 6;
  float y = conv_b[tid];                        // conv of all-zero input
  float s = y;
  for (int off = 32; off; off >>= 1) s += __shfl_down(s, off);
  if (lane == 0) red[wv] = s;
  __syncthreads();
  float mean = (red[0] + red[1] + red[2] + red[3]) * (1.0f / H);
  float d = y - mean, q = d * d;
  for (int off = 32; off; off >>= 1) q += __shfl_down(q, off);
  if (lane == 0) red[4 + wv] = q;
  __syncthreads();
  float var = (red[4] + red[5] + red[6] + red[7]) * (1.0f / H);
  float h = d / sqrtf(var + 1e-5f) * ln_g[tid] + ln_b[tid];
  h = h > 0.f ? h : 0.01f * h;
  hc[tid] = h;
  __syncthreads();
  float am = 0.f, ae = 0.f;
  for (int cin = 0; cin < H; ++cin) {
    float hv = hc[cin];
    float p0 = post_w[(0 * H + cin) * H + tid];
    float p1 = post_w[(1 * H + cin) * H + tid];
    float p2 = post_w[(2 * H + cin) * H + tid];
    am += (p0 + p1 + p2) * hv;                  // interior position
    ae += (p0 + p1) * hv;                       // last position (right zero-pad)
  }
  zm[tid] = am + post_b[tid];
  ze[tid] = ae + post_b[tid];
  __syncthreads();
  if (tid < NOTE_CLS) {
    float sm = 0.f, se = 0.f;
    for (int c = 0; c < H; ++c) {
      float w = w_pitch[c * NOTE_CLS + tid];
      sm += zm[c] * w; se += ze[c] * w;
    }
    lm[tid] = sm + b_pitch[tid]; le[tid] = se + b_pitch[tid];
    lmid[tid] = lm[tid]; ledge[tid] = le[tid];
  }
  __syncthreads();
  if (tid == 0) {
    int bi = 0; float bv = lm[0];
    for (int p = 1; p < NOTE_CLS; ++p) if (lm[p] > bv) { bv = lm[p]; bi = p; }
    preds[0] = (bi > NOTE_NUM || bi < NOTE_START) ? 0 : bi;
    bi = 0; bv = le[0];
    for (int p = 1; p < NOTE_CLS; ++p) if (le[p] > bv) { bv = le[p]; bi = p; }
    preds[1] = (bi > NOTE_NUM || bi < NOTE_START) ? 0 : bi;
  }
}

// ---------------- Kernel 4: segment weighted means ---------------------------
__global__ __launch_bounds__(64) void k_seg(
    const float* __restrict__ feat, const float* __restrict__ amean,
    const int* __restrict__ seg_start, const int* __restrict__ note_len,
    float* __restrict__ agg)
{
  int blk = blockIdx.x;
  int b = blk / NSEG, n = blk - b * NSEG;
  int len = note_len[b];
  int lane = threadIdx.x;
  float4* o4 = (float4*)(agg + ((size_t)b * NSEG + n) * H);
  if (n >= len) {
    if (n < len + TILE + 8) o4[lane] = make_float4(0.f, 0.f, 0.f, 0.f);
    return;
  }
  int s = seg_start[b * (T + 2) + n];
  int e = seg_start[b * (T + 2) + n + 1];
  float4 acc = make_float4(0.f, 0.f, 0.f, 0.f);
  float dsum = 0.f;
  for (int t = s; t < e; ++t) {
    float am = amean[(size_t)b * T + t];
    float4 f = ((const float4*)(feat + ((size_t)b * T + t) * H))[lane];
    acc.x += am * f.x; acc.y += am * f.y; acc.z += am * f.z; acc.w += am * f.w;
    dsum += am;
  }
  float dn = dsum + 1e-5f;
  acc.x /= dn; acc.y /= dn; acc.z /= dn; acc.w /= dn;
  o4[lane] = acc;
}

// ---------------- Kernel 5: conv -> LN -> leaky -> conv -> pitch -> argmax ---
__global__ __launch_bounds__(256) void k_conv_full(
    const float* __restrict__ agg,
    const float* __restrict__ conv_w, const float* __restrict__ conv_b,
    const float* __restrict__ ln_g, const float* __restrict__ ln_b,
    const float* __restrict__ post_w, const float* __restrict__ post_b,
    const float* __restrict__ w_pitch, const float* __restrict__ b_pitch,
    const int* __restrict__ note_len,
    float* __restrict__ out3, float* __restrict__ out4)
{
  int blk = blockIdx.x;
  int b = blk / NT, tile = blk - b * NT;
  int t0 = tile * TILE;
  int len = note_len[b];
  if (t0 > len + 2) return;                      // tail kernel handles the rest

  __shared__ float xs[H][XSTR];                  // agg transposed [c][r], later z [c][n]
  __shared__ float us[H][XSTR];                  // u transposed   [c][m]
  __shared__ float rs_[YR][4], rq_[YR][4];
  __shared__ float stat_mean[YR], stat_rstd[YR];
  __shared__ float pvs[TILE][26];
  __shared__ int   pis[TILE][26];

  int tid = threadIdx.x, lane = tid & 63, wv = tid >> 6;
  const float* aggb = agg + (size_t)b * NSEG * H;

  // load agg tile+halo (zero-filled region of agg covers p >= len)
  #pragma unroll 1
  for (int r = 0; r < XR; ++r) {
    int p = t0 - 2 + r;
    float v = 0.f;
    if (p >= 0 && p < NSEG) v = aggb[(size_t)p * H + tid];
    xs[tid][r] = v;
  }
  __syncthreads();

  // conv1: thread = cout; y positions t0-1+m, m=0..33
  float acc[YR];
  #pragma unroll
  for (int m = 0; m < YR; ++m) acc[m] = 0.f;
  #pragma unroll 2
  for (int cin = 0; cin < H; ++cin) {
    float w0 = conv_w[(0 * H + cin) * H + tid];
    float w1 = conv_w[(1 * H + cin) * H + tid];
    float w2 = conv_w[(2 * H + cin) * H + tid];
    float xv[XR];
    #pragma unroll
    for (int qq = 0; qq < XR / 4; ++qq) {
      float4 t4 = *(const float4*)&xs[cin][4 * qq];
      xv[4 * qq + 0] = t4.x; xv[4 * qq + 1] = t4.y; xv[4 * qq + 2] = t4.z; xv[4 * qq + 3] = t4.w;
    }
    #pragma unroll
    for (int m = 0; m < YR; ++m)
      acc[m] += w0 * xv[m] + w1 * xv[m + 1] + w2 * xv[m + 2];
  }
  {
    float cb = conv_b[tid];
    #pragma unroll
    for (int m = 0; m < YR; ++m) acc[m] += cb;
  }

  // LN stats per position (reduce over channels)
  #pragma unroll 1
  for (int m = 0; m < YR; ++m) {
    float s = acc[m], q = acc[m] * acc[m];
    for (int off = 32; off; off >>= 1) { s += __shfl_down(s, off); q += __shfl_down(q, off); }
    if (lane == 0) { rs_[m][wv] = s; rq_[m][wv] = q; }
  }
  __syncthreads();
  if (tid < YR) {
    float S = rs_[tid][0] + rs_[tid][1] + rs_[tid][2] + rs_[tid][3];
    float Q = rq_[tid][0] + rq_[tid][1] + rq_[tid][2] + rq_[tid][3];
    float mean = S * (1.0f / H);
    float var = Q * (1.0f / H) - mean * mean;
    if (var < 0.f) var = 0.f;
    stat_mean[tid] = mean;
    stat_rstd[tid] = 1.0f / sqrtf(var + 1e-5f);
  }
  __syncthreads();

  // u = agg + leaky(LN(y));  u = 0 at pad positions (p<0 or p>=NPOS)
  {
    float g = ln_g[tid], bb = ln_b[tid];
    #pragma unroll 1
    for (int m = 0; m < YR; ++m) {
      int p = t0 - 1 + m;
      float h = (acc[m] - stat_mean[m]) * stat_rstd[m] * g + bb;
      h = h > 0.f ? h : 0.01f * h;
      float u = 0.f;
      if (p >= 0 && p < NPOS) u = aggb[(size_t)p * H + tid] + h;
      us[tid][m] = u;
    }
    us[tid][34] = 0.f; us[tid][35] = 0.f;
  }
  __syncthreads();

  // post conv: z positions t0+n, n=0..31
  float acc2[TILE];
  #pragma unroll
  for (int n = 0; n < TILE; ++n) acc2[n] = 0.f;
  #pragma unroll 2
  for (int cin = 0; cin < H; ++cin) {
    float w0 = post_w[(0 * H + cin) * H + tid];
    float w1 = post_w[(1 * H + cin) * H + tid];
    float w2 = post_w[(2 * H + cin) * H + tid];
    float uv[XR];
    #pragma unroll
    for (int qq = 0; qq < XR / 4; ++qq) {
      float4 t4 = *(const float4*)&us[cin][4 * qq];
      uv[4 * qq + 0] = t4.x; uv[4 * qq + 1] = t4.y; uv[4 * qq + 2] = t4.z; uv[4 * qq + 3] = t4.w;
    }
    #pragma unroll
    for (int n = 0; n < TILE; ++n)
      acc2[n] += w0 * uv[n] + w1 * uv[n + 1] + w2 * uv[n + 2];
  }
  float pb_ = post_b[tid];
  __syncthreads();
  #pragma unroll
  for (int n = 0; n < TILE; ++n) xs[tid][n] = acc2[n] + pb_;   // z into xs region
  __syncthreads();

  // pitch head: 8 n-blocks x 26 p-blocks of 4 (208 active threads)
  {
    int nb = tid / 26, pbi = tid - nb * 26;
    if (nb < 8) {
      float4 ap0 = make_float4(0,0,0,0), ap1 = ap0, ap2 = ap0, ap3 = ap0;
      #pragma unroll 2
      for (int cin = 0; cin < H; ++cin) {
        float4 zv = *(const float4*)&xs[cin][4 * nb];
        float4 wv4 = *(const float4*)&w_pitch[cin * NOTE_CLS + 4 * pbi];
        ap0.x += zv.x * wv4.x; ap0.y += zv.x * wv4.y; ap0.z += zv.x * wv4.z; ap0.w += zv.x * wv4.w;
        ap1.x += zv.y * wv4.x; ap1.y += zv.y * wv4.y; ap1.z += zv.y * wv4.z; ap1.w += zv.y * wv4.w;
        ap2.x += zv.z * wv4.x; ap2.y += zv.z * wv4.y; ap2.z += zv.z * wv4.z; ap2.w += zv.z * wv4.w;
        ap3.x += zv.w * wv4.x; ap3.y += zv.w * wv4.y; ap3.z += zv.w * wv4.z; ap3.w += zv.w * wv4.w;
      }
      float4 bp = *(const float4*)&b_pitch[4 * pbi];
      float4 aps[4] = { ap0, ap1, ap2, ap3 };
      #pragma unroll
      for (int j = 0; j < 4; ++j) {
        int n = 4 * nb + j;
        float4 o;
        o.x = aps[j].x + bp.x; o.y = aps[j].y + bp.y;
        o.z = aps[j].z + bp.z; o.w = aps[j].w + bp.w;
        *(float4*)&out3[((size_t)b * NPOS + (t0 + n)) * NOTE_CLS + 4 * pbi] = o;
        float bv = o.x; int bi = 4 * pbi;
        if (o.y > bv) { bv = o.y; bi = 4 * pbi + 1; }
        if (o.z > bv) { bv = o.z; bi = 4 * pbi + 2; }
        if (o.w > bv) { bv = o.w; bi = 4 * pbi + 3; }
        pvs[n][pbi] = bv; pis[n][pbi] = bi;
      }
    }
  }
  __syncthreads();
  if (tid < TILE) {
    float bv = pvs[tid][0]; int bi = pis[tid][0];
    #pragma unroll 1
    for (int k = 1; k < 26; ++k)
      if (pvs[tid][k] > bv) { bv = pvs[tid][k]; bi = pis[tid][k]; }
    int pred = (bi > NOTE_NUM || bi < NOTE_START) ? 0 : bi;
    out4[(size_t)b * NPOS + t0 + tid] = (float)pred;
  }
}

// ---------------- Kernel 6: constant tail broadcast --------------------------
__global__ __launch_bounds__(256) void k_tail(
    const float* __restrict__ lmid, const float* __restrict__ ledge,
    const int* __restrict__ preds, const int* __restrict__ note_len,
    float* __restrict__ out3, float* __restrict__ out4)
{
  int blk = blockIdx.x;
  int b = blk / NT, tile = blk - b * NT;
  int t0 = tile * TILE;
  int len = note_len[b];
  if (t0 <= len + 2) return;                    // handled by k_conv_full
  __shared__ float lm[NOTE_CLS], le[NOTE_CLS];
  int tid = threadIdx.x;
  if (tid < NOTE_CLS) { lm[tid] = lmid[tid]; le[tid] = ledge[tid]; }
  __syncthreads();
  int pm = preds[0], pe = preds[1];
  for (int i = tid; i < TILE * NOTE_CLS; i += 256) {
    int n = t0 + i / NOTE_CLS, p = i - (i / NOTE_CLS) * NOTE_CLS;
    if (n >= NPOS) continue;
    out3[((size_t)b * NPOS + n) * NOTE_CLS + p] = (n == NPOS - 1) ? le[p] : lm[p];
  }
  if (tid < TILE) {
    int n = t0 + tid;
    if (n < NPOS) out4[(size_t)b * NPOS + n] = (float)((n == NPOS - 1) ? pe : pm);
  }
}

// ---------------- launcher ---------------------------------------------------
extern "C" void kernel_launch(void* const* d_in, const int* in_sizes, int n_in,
                              void* d_out, int out_size, void* d_ws, size_t ws_size,
                              hipStream_t stream) {
  (void)in_sizes; (void)n_in; (void)out_size; (void)ws_size;
  const float* feat    = (const float*)d_in[0];
  const int*   nonpad  = (const int*)d_in[1];
  const float* w_bd    = (const float*)d_in[2];
  const float* b_bd    = (const float*)d_in[3];
  const float* w_attn  = (const float*)d_in[4];
  const float* b_attn  = (const float*)d_in[5];
  const float* conv_w  = (const float*)d_in[6];
  const float* conv_b  = (const float*)d_in[7];
  const float* ln_g    = (const float*)d_in[8];
  const float* ln_b    = (const float*)d_in[9];
  const float* post_w  = (const float*)d_in[10];
  const float* post_b  = (const float*)d_in[11];
  const float* w_pitch = (const float*)d_in[12];
  const float* b_pitch = (const float*)d_in[13];

  float* out  = (float*)d_out;
  float* out0 = out;                                  // [B,T] note_bd_logits
  float* out1 = out + (size_t)B * T;                  // [B,T] note_bd
  float* out2 = out + 2ull * B * T;                   // [B]   note_lengths
  float* out3 = out2 + B;                             // [B,NPOS,104] note_logits
  float* out4 = out3 + (size_t)B * NPOS * NOTE_CLS;   // [B,NPOS] note_pred

  char* ws = (char*)d_ws;
  double* dlog  = (double*)(ws + 0);                  // 768000 B
  float*  amean = (float*)(ws + 768000);              // 384000 B
  int*    segst = (int*)(ws + 1152000);               // 384128 B
  int*    nlen  = (int*)(ws + 1536128);               // 64 B
  float*  lmid  = (float*)(ws + 1536192);             // 416 B
  float*  ledge = (float*)(ws + 1536608);             // 416 B
  int*    preds = (int*)(ws + 1537024);               // 8 B
  float*  agg   = (float*)(ws + 1537536);             // 16*1024*256*4 = 16.78 MB

  k_dots<<<(B * T) / 4, 256, 0, stream>>>(feat, w_bd, b_bd, w_attn, b_attn, out0, dlog, amean);
  k_regulate<<<B, 64, 0, stream>>>(dlog, nonpad, out1, out2, segst, nlen);
  k_consts<<<1, 256, 0, stream>>>(conv_b, ln_g, ln_b, post_w, post_b, w_pitch, b_pitch, lmid, ledge, preds);
  k_seg<<<B * NSEG, 64, 0, stream>>>(feat, amean, segst, nlen, agg);
  k_conv_full<<<B * NT, 256, 0, stream>>>(agg, conv_w, conv_b, ln_g, ln_b, post_w, post_b,
                                          w_pitch, b_pitch, nlen, out3, out4);
  k_tail<<<B * NT, 256, 0, stream>>>(lmid, ledge, preds, nlen, out3, out4);
}

// Round 2
// 520.868 us; speedup vs baseline: 2.1855x; 2.1855x over previous
//
#include <hip/hip_runtime.h>
#include <math.h>

#define B 16
#define T 6000
#define H 256
#define NPOS 6001            // T+1 segments
#define NOTE_CLS 104
#define NOTE_NUM 100
#define NOTE_START 30
#define MIN_GAP 9
#define NSEG 1024            // cap on materialized segments (actual max len ~255)
#define TILE 32
#define NT ((NPOS + TILE - 1) / TILE)   // 188
#define XR 36                // agg rows per tile: [t0-2, t0+TILE+1]
#define YR 34                // y/u rows per tile: [t0-1, t0+TILE]
#define XSTR 40              // padded LDS row stride (16B-aligned)

#define NWORDS 94            // ceil(T/64)
#define MAXRUNS 3088         // ceil(T/2) rounded up + pad for unroll-8

// ---------------- Kernel 1: bd + attn dot products (f64 accumulate) ----------
__global__ __launch_bounds__(256) void k_dots(
    const float* __restrict__ feat,
    const float* __restrict__ w_bd, const float* __restrict__ b_bd,
    const float* __restrict__ w_attn, const float* __restrict__ b_attn,
    float* __restrict__ out_logits, double* __restrict__ dlog,
    float* __restrict__ amean)
{
  int lane = threadIdx.x & 63, wv = threadIdx.x >> 6;
  int row = blockIdx.x * 4 + wv;                      // b*T + t
  if (row >= B * T) return;
  float4 f  = ((const float4*)(feat + (size_t)row * H))[lane];
  float4 wb = ((const float4*)w_bd)[lane];
  float4 wa = ((const float4*)w_attn)[lane];
  double sb = (double)f.x * wb.x + (double)f.y * wb.y + (double)f.z * wb.z + (double)f.w * wb.w;
  double sa = (double)f.x * wa.x + (double)f.y * wa.y + (double)f.z * wa.z + (double)f.w * wa.w;
  for (int off = 32; off; off >>= 1) { sb += __shfl_down(sb, off); sa += __shfl_down(sa, off); }
  if (lane == 0) {
    double lb = sb + (double)b_bd[0];
    lb = fmin(fmax(lb, -16.0), 16.0);
    out_logits[row] = (float)lb;
    dlog[row] = lb;
    double la = sa + (double)b_attn[0];
    amean[row] = (float)(1.0 / (1.0 + exp(-la)));
  }
}

// ---------------- Kernel 2: regulate_boundary (run-decomposed) ---------------
// Phase A (parallel): bits -> packed words -> run starts (ballot compaction)
// Phase B (parallel): per-run argmax walks (strict >, first occurrence)
// Phase C (serial over ~1500 runs, per-row): merge chain on best_i only
// Phase D (parallel): outputs
__global__ __launch_bounds__(256) void k_regulate(
    const double* __restrict__ dlog, const int* __restrict__ non_padding,
    float* __restrict__ out_bd, float* __restrict__ out_len,
    int* __restrict__ seg_start, int* __restrict__ note_len)
{
  __shared__ unsigned long long words[96];
  __shared__ unsigned long long smask[96];
  __shared__ int wcnt[96], woff[96];
  __shared__ int starts_s[MAXRUNS];
  __shared__ int besti_s[MAXRUNS];
  __shared__ int list_s[3072];
  __shared__ int red_i[4];
  __shared__ int R_s, lens_s, keep_s, cnt_chain_s;

  int b = blockIdx.x, tid = threadIdx.x;
  int lane = tid & 63, wv = tid >> 6;
  const double* row = dlog + (size_t)b * T;

  // pad besti so the chain's unroll-8 loads are always in-bounds
  for (int i = tid; i < MAXRUNS; i += 256) besti_s[i] = 0;

  // --- Phase A: bits -> words ---
  for (int c = 0; c < 24; ++c) {
    int t = c * 256 + tid;
    bool bit = (t < T) && (row[t] > 0.0);
    unsigned long long m = __ballot(bit ? 1 : 0);
    if (lane == 0) words[c * 4 + wv] = m;
  }
  __syncthreads();

  // run-start masks + per-word counts
  if (tid < NWORDS) {
    unsigned long long bits = words[tid];
    unsigned long long carry = (tid > 0) ? (words[tid - 1] >> 63) : 0ull;
    unsigned long long sm = bits & ~((bits << 1) | carry);
    smask[tid] = sm;
    wcnt[tid] = __popcll(sm);
  }
  __syncthreads();

  // exclusive prefix over word counts (serial, tiny)
  if (tid == 0) {
    int acc = 0;
    #pragma unroll 8
    for (int w = 0; w < NWORDS; ++w) { woff[w] = acc; acc += wcnt[w]; }
    R_s = acc;
  }
  __syncthreads();

  // compact run starts (ascending within word, words ascending)
  if (tid < NWORDS) {
    unsigned long long m = smask[tid];
    int off = woff[tid];
    int base = tid * 64;
    while (m) {
      int i = __builtin_ctzll(m);
      starts_s[off++] = base + i;
      m &= m - 1;
    }
  }
  __syncthreads();

  int R = R_s;
  int bd_last = (int)((words[(T - 1) >> 6] >> ((T - 1) & 63)) & 1ull);
  int Rc = R - (bd_last ? 1 : 0);          // only the trailing run can be unclosed

  // --- Phase B: per-run argmax walks ---
  for (int r = tid; r < R; r += 256) {
    int s = starts_s[r];
    double bv = row[s];
    int bi = s;
    for (int t = s + 1; t < T; ++t) {
      double d = row[t];
      if (!(d > 0.0)) break;
      if (d > bv) { bv = d; bi = t; }
    }
    besti_s[r] = bi;
  }

  // lens = sum(non_padding[b])
  int lens = 0;
  const int* npr = non_padding + (size_t)b * T;
  for (int t = tid; t < T; t += 256) lens += npr[t];
  for (int off = 32; off; off >>= 1) lens += __shfl_down(lens, off);
  if (lane == 0) red_i[wv] = lens;
  __syncthreads();
  if (tid == 0) lens_s = red_i[0] + red_i[1] + red_i[2] + red_i[3];
  __syncthreads();
  lens = lens_s;

  // --- Phase C: merge chain (thread 0), batched LDS loads ---
  if (tid == 0) {
    int cnt = 0, last = -1;
    for (int r0 = 0; r0 < Rc; r0 += 8) {
      int v[8];
      #pragma unroll
      for (int k = 0; k < 8; ++k) v[k] = besti_s[r0 + k];
      int kmax = Rc - r0; if (kmax > 8) kmax = 8;
      for (int k = 0; k < kmax; ++k) {
        int bi = v[k];
        bool merge = (last > 0) && (bi - last < MIN_GAP);
        int fi = bi;
        if (merge) { int s = bi + last; fi = (s + ((s >> 1) & 1)) >> 1; }  // half-to-even
        if (merge) list_s[cnt - 1] = fi;
        else       list_s[cnt++]   = fi;
        last = fi;
      }
    }
    cnt_chain_s = cnt;
    // filter: res[0]=0 and res[t >= lens-1]=0
    int keep = 0;
    for (int i = 0; i < cnt; ++i) {
      int e = list_s[i];
      if (e != 0 && e < lens - 1) list_s[keep++] = e;
    }
    keep_s = keep;
  }
  __syncthreads();
  int keep = keep_s;

  // --- Phase D: outputs ---
  float* obd = out_bd + (size_t)b * T;
  for (int t = tid; t < T; t += 256) obd[t] = 0.f;
  __syncthreads();                           // order zeros before ones (block fence)
  int* ss = seg_start + b * (T + 2);
  for (int i = tid; i < keep; i += 256) {
    int e = list_s[i];
    obd[e] = 1.f;
    ss[i + 1] = e;
  }
  if (tid == 0) {
    ss[0] = 0;
    ss[keep + 1] = T;                        // sentinel end of last segment
    note_len[b] = keep + 1;
    out_len[b] = (float)(keep + 1);
  }
}

// ---------------- Kernel 3: constant tail logits (zero-agg positions) --------
__global__ __launch_bounds__(256) void k_consts(
    const float* __restrict__ conv_b, const float* __restrict__ ln_g,
    const float* __restrict__ ln_b, const float* __restrict__ post_w,
    const float* __restrict__ post_b, const float* __restrict__ w_pitch,
    const float* __restrict__ b_pitch,
    float* __restrict__ lmid, float* __restrict__ ledge, int* __restrict__ preds)
{
  __shared__ float hc[H], zm[H], ze[H], red[8];
  __shared__ float lm[NOTE_CLS], le[NOTE_CLS];
  int tid = threadIdx.x, lane = tid & 63, wv = tid >> 6;
  float y = conv_b[tid];                        // conv of all-zero input
  float s = y;
  for (int off = 32; off; off >>= 1) s += __shfl_down(s, off);
  if (lane == 0) red[wv] = s;
  __syncthreads();
  float mean = (red[0] + red[1] + red[2] + red[3]) * (1.0f / H);
  float d = y - mean, q = d * d;
  for (int off = 32; off; off >>= 1) q += __shfl_down(q, off);
  if (lane == 0) red[4 + wv] = q;
  __syncthreads();
  float var = (red[4] + red[5] + red[6] + red[7]) * (1.0f / H);
  float h = d / sqrtf(var + 1e-5f) * ln_g[tid] + ln_b[tid];
  h = h > 0.f ? h : 0.01f * h;
  hc[tid] = h;
  __syncthreads();
  float am = 0.f, ae = 0.f;
  for (int cin = 0; cin < H; ++cin) {
    float hv = hc[cin];
    float p0 = post_w[(0 * H + cin) * H + tid];
    float p1 = post_w[(1 * H + cin) * H + tid];
    float p2 = post_w[(2 * H + cin) * H + tid];
    am += (p0 + p1 + p2) * hv;                  // interior position
    ae += (p0 + p1) * hv;                       // last position (right zero-pad)
  }
  zm[tid] = am + post_b[tid];
  ze[tid] = ae + post_b[tid];
  __syncthreads();
  if (tid < NOTE_CLS) {
    float sm = 0.f, se = 0.f;
    for (int c = 0; c < H; ++c) {
      float w = w_pitch[c * NOTE_CLS + tid];
      sm += zm[c] * w; se += ze[c] * w;
    }
    lm[tid] = sm + b_pitch[tid]; le[tid] = se + b_pitch[tid];
    lmid[tid] = lm[tid]; ledge[tid] = le[tid];
  }
  __syncthreads();
  if (tid == 0) {
    int bi = 0; float bv = lm[0];
    for (int p = 1; p < NOTE_CLS; ++p) if (lm[p] > bv) { bv = lm[p]; bi = p; }
    preds[0] = (bi > NOTE_NUM || bi < NOTE_START) ? 0 : bi;
    bi = 0; bv = le[0];
    for (int p = 1; p < NOTE_CLS; ++p) if (le[p] > bv) { bv = le[p]; bi = p; }
    preds[1] = (bi > NOTE_NUM || bi < NOTE_START) ? 0 : bi;
  }
}

// ---------------- Kernel 4: segment weighted means ---------------------------
__global__ __launch_bounds__(64) void k_seg(
    const float* __restrict__ feat, const float* __restrict__ amean,
    const int* __restrict__ seg_start, const int* __restrict__ note_len,
    float* __restrict__ agg)
{
  int blk = blockIdx.x;
  int b = blk / NSEG, n = blk - b * NSEG;
  int len = note_len[b];
  int lane = threadIdx.x;
  float4* o4 = (float4*)(agg + ((size_t)b * NSEG + n) * H);
  if (n >= len) {
    if (n < len + TILE + 8) o4[lane] = make_float4(0.f, 0.f, 0.f, 0.f);
    return;
  }
  int s = seg_start[b * (T + 2) + n];
  int e = seg_start[b * (T + 2) + n + 1];
  float4 acc = make_float4(0.f, 0.f, 0.f, 0.f);
  float dsum = 0.f;
  for (int t = s; t < e; ++t) {
    float am = amean[(size_t)b * T + t];
    float4 f = ((const float4*)(feat + ((size_t)b * T + t) * H))[lane];
    acc.x += am * f.x; acc.y += am * f.y; acc.z += am * f.z; acc.w += am * f.w;
    dsum += am;
  }
  float dn = dsum + 1e-5f;
  acc.x /= dn; acc.y /= dn; acc.z /= dn; acc.w /= dn;
  o4[lane] = acc;
}

// ---------------- Kernel 5: conv -> LN -> leaky -> conv -> pitch -> argmax ---
__global__ __launch_bounds__(256) void k_conv_full(
    const float* __restrict__ agg,
    const float* __restrict__ conv_w, const float* __restrict__ conv_b,
    const float* __restrict__ ln_g, const float* __restrict__ ln_b,
    const float* __restrict__ post_w, const float* __restrict__ post_b,
    const float* __restrict__ w_pitch, const float* __restrict__ b_pitch,
    const int* __restrict__ note_len,
    float* __restrict__ out3, float* __restrict__ out4)
{
  int blk = blockIdx.x;
  int b = blk / NT, tile = blk - b * NT;
  int t0 = tile * TILE;
  int len = note_len[b];
  if (t0 > len + 2) return;                      // tail kernel handles the rest

  __shared__ float xs[H][XSTR];                  // agg transposed [c][r], later z [c][n]
  __shared__ float us[H][XSTR];                  // u transposed   [c][m]
  __shared__ float rs_[YR][4], rq_[YR][4];
  __shared__ float stat_mean[YR], stat_rstd[YR];
  __shared__ float pvs[TILE][26];
  __shared__ int   pis[TILE][26];

  int tid = threadIdx.x, lane = tid & 63, wv = tid >> 6;
  const float* aggb = agg + (size_t)b * NSEG * H;

  // load agg tile+halo (zero-filled region of agg covers p >= len)
  #pragma unroll 1
  for (int r = 0; r < XR; ++r) {
    int p = t0 - 2 + r;
    float v = 0.f;
    if (p >= 0 && p < NSEG) v = aggb[(size_t)p * H + tid];
    xs[tid][r] = v;
  }
  __syncthreads();

  // conv1: thread = cout; y positions t0-1+m, m=0..33
  float acc[YR];
  #pragma unroll
  for (int m = 0; m < YR; ++m) acc[m] = 0.f;
  #pragma unroll 2
  for (int cin = 0; cin < H; ++cin) {
    float w0 = conv_w[(0 * H + cin) * H + tid];
    float w1 = conv_w[(1 * H + cin) * H + tid];
    float w2 = conv_w[(2 * H + cin) * H + tid];
    float xv[XR];
    #pragma unroll
    for (int qq = 0; qq < XR / 4; ++qq) {
      float4 t4 = *(const float4*)&xs[cin][4 * qq];
      xv[4 * qq + 0] = t4.x; xv[4 * qq + 1] = t4.y; xv[4 * qq + 2] = t4.z; xv[4 * qq + 3] = t4.w;
    }
    #pragma unroll
    for (int m = 0; m < YR; ++m)
      acc[m] += w0 * xv[m] + w1 * xv[m + 1] + w2 * xv[m + 2];
  }
  {
    float cb = conv_b[tid];
    #pragma unroll
    for (int m = 0; m < YR; ++m) acc[m] += cb;
  }

  // LN stats per position (reduce over channels)
  #pragma unroll 1
  for (int m = 0; m < YR; ++m) {
    float s = acc[m], q = acc[m] * acc[m];
    for (int off = 32; off; off >>= 1) { s += __shfl_down(s, off); q += __shfl_down(q, off); }
    if (lane == 0) { rs_[m][wv] = s; rq_[m][wv] = q; }
  }
  __syncthreads();
  if (tid < YR) {
    float S = rs_[tid][0] + rs_[tid][1] + rs_[tid][2] + rs_[tid][3];
    float Q = rq_[tid][0] + rq_[tid][1] + rq_[tid][2] + rq_[tid][3];
    float mean = S * (1.0f / H);
    float var = Q * (1.0f / H) - mean * mean;
    if (var < 0.f) var = 0.f;
    stat_mean[tid] = mean;
    stat_rstd[tid] = 1.0f / sqrtf(var + 1e-5f);
  }
  __syncthreads();

  // u = agg + leaky(LN(y));  u = 0 at pad positions (p<0 or p>=NPOS)
  {
    float g = ln_g[tid], bb = ln_b[tid];
    #pragma unroll 1
    for (int m = 0; m < YR; ++m) {
      int p = t0 - 1 + m;
      float h = (acc[m] - stat_mean[m]) * stat_rstd[m] * g + bb;
      h = h > 0.f ? h : 0.01f * h;
      float u = 0.f;
      if (p >= 0 && p < NPOS) u = aggb[(size_t)p * H + tid] + h;
      us[tid][m] = u;
    }
    us[tid][34] = 0.f; us[tid][35] = 0.f;
  }
  __syncthreads();

  // post conv: z positions t0+n, n=0..31
  float acc2[TILE];
  #pragma unroll
  for (int n = 0; n < TILE; ++n) acc2[n] = 0.f;
  #pragma unroll 2
  for (int cin = 0; cin < H; ++cin) {
    float w0 = post_w[(0 * H + cin) * H + tid];
    float w1 = post_w[(1 * H + cin) * H + tid];
    float w2 = post_w[(2 * H + cin) * H + tid];
    float uv[XR];
    #pragma unroll
    for (int qq = 0; qq < XR / 4; ++qq) {
      float4 t4 = *(const float4*)&us[cin][4 * qq];
      uv[4 * qq + 0] = t4.x; uv[4 * qq + 1] = t4.y; uv[4 * qq + 2] = t4.z; uv[4 * qq + 3] = t4.w;
    }
    #pragma unroll
    for (int n = 0; n < TILE; ++n)
      acc2[n] += w0 * uv[n] + w1 * uv[n + 1] + w2 * uv[n + 2];
  }
  float pb_ = post_b[tid];
  __syncthreads();
  #pragma unroll
  for (int n = 0; n < TILE; ++n) xs[tid][n] = acc2[n] + pb_;   // z into xs region
  __syncthreads();

  // pitch head: 8 n-blocks x 26 p-blocks of 4 (208 active threads)
  {
    int nb = tid / 26, pbi = tid - nb * 26;
    if (nb < 8) {
      float4 ap0 = make_float4(0,0,0,0), ap1 = ap0, ap2 = ap0, ap3 = ap0;
      #pragma unroll 2
      for (int cin = 0; cin < H; ++cin) {
        float4 zv = *(const float4*)&xs[cin][4 * nb];
        float4 wv4 = *(const float4*)&w_pitch[cin * NOTE_CLS + 4 * pbi];
        ap0.x += zv.x * wv4.x; ap0.y += zv.x * wv4.y; ap0.z += zv.x * wv4.z; ap0.w += zv.x * wv4.w;
        ap1.x += zv.y * wv4.x; ap1.y += zv.y * wv4.y; ap1.z += zv.y * wv4.z; ap1.w += zv.y * wv4.w;
        ap2.x += zv.z * wv4.x; ap2.y += zv.z * wv4.y; ap2.z += zv.z * wv4.z; ap2.w += zv.z * wv4.w;
        ap3.x += zv.w * wv4.x; ap3.y += zv.w * wv4.y; ap3.z += zv.w * wv4.z; ap3.w += zv.w * wv4.w;
      }
      float4 bp = *(const float4*)&b_pitch[4 * pbi];
      float4 aps[4] = { ap0, ap1, ap2, ap3 };
      #pragma unroll
      for (int j = 0; j < 4; ++j) {
        int n = 4 * nb + j;
        float4 o;
        o.x = aps[j].x + bp.x; o.y = aps[j].y + bp.y;
        o.z = aps[j].z + bp.z; o.w = aps[j].w + bp.w;
        *(float4*)&out3[((size_t)b * NPOS + (t0 + n)) * NOTE_CLS + 4 * pbi] = o;
        float bv = o.x; int bi = 4 * pbi;
        if (o.y > bv) { bv = o.y; bi = 4 * pbi + 1; }
        if (o.z > bv) { bv = o.z; bi = 4 * pbi + 2; }
        if (o.w > bv) { bv = o.w; bi = 4 * pbi + 3; }
        pvs[n][pbi] = bv; pis[n][pbi] = bi;
      }
    }
  }
  __syncthreads();
  if (tid < TILE) {
    float bv = pvs[tid][0]; int bi = pis[tid][0];
    #pragma unroll 1
    for (int k = 1; k < 26; ++k)
      if (pvs[tid][k] > bv) { bv = pvs[tid][k]; bi = pis[tid][k]; }
    int pred = (bi > NOTE_NUM || bi < NOTE_START) ? 0 : bi;
    out4[(size_t)b * NPOS + t0 + tid] = (float)pred;
  }
}

// ---------------- Kernel 6: constant tail broadcast --------------------------
__global__ __launch_bounds__(256) void k_tail(
    const float* __restrict__ lmid, const float* __restrict__ ledge,
    const int* __restrict__ preds, const int* __restrict__ note_len,
    float* __restrict__ out3, float* __restrict__ out4)
{
  int blk = blockIdx.x;
  int b = blk / NT, tile = blk - b * NT;
  int t0 = tile * TILE;
  int len = note_len[b];
  if (t0 <= len + 2) return;                    // handled by k_conv_full
  __shared__ float lm[NOTE_CLS], le[NOTE_CLS];
  int tid = threadIdx.x;
  if (tid < NOTE_CLS) { lm[tid] = lmid[tid]; le[tid] = ledge[tid]; }
  __syncthreads();
  int pm = preds[0], pe = preds[1];
  for (int i = tid; i < TILE * NOTE_CLS; i += 256) {
    int n = t0 + i / NOTE_CLS, p = i - (i / NOTE_CLS) * NOTE_CLS;
    if (n >= NPOS) continue;
    out3[((size_t)b * NPOS + n) * NOTE_CLS + p] = (n == NPOS - 1) ? le[p] : lm[p];
  }
  if (tid < TILE) {
    int n = t0 + tid;
    if (n < NPOS) out4[(size_t)b * NPOS + n] = (float)((n == NPOS - 1) ? pe : pm);
  }
}

// ---------------- launcher ---------------------------------------------------
extern "C" void kernel_launch(void* const* d_in, const int* in_sizes, int n_in,
                              void* d_out, int out_size, void* d_ws, size_t ws_size,
                              hipStream_t stream) {
  (void)in_sizes; (void)n_in; (void)out_size; (void)ws_size;
  const float* feat    = (const float*)d_in[0];
  const int*   nonpad  = (const int*)d_in[1];
  const float* w_bd    = (const float*)d_in[2];
  const float* b_bd    = (const float*)d_in[3];
  const float* w_attn  = (const float*)d_in[4];
  const float* b_attn  = (const float*)d_in[5];
  const float* conv_w  = (const float*)d_in[6];
  const float* conv_b  = (const float*)d_in[7];
  const float* ln_g    = (const float*)d_in[8];
  const float* ln_b    = (const float*)d_in[9];
  const float* post_w  = (const float*)d_in[10];
  const float* post_b  = (const float*)d_in[11];
  const float* w_pitch = (const float*)d_in[12];
  const float* b_pitch = (const float*)d_in[13];

  float* out  = (float*)d_out;
  float* out0 = out;                                  // [B,T] note_bd_logits
  float* out1 = out + (size_t)B * T;                  // [B,T] note_bd
  float* out2 = out + 2ull * B * T;                   // [B]   note_lengths
  float* out3 = out2 + B;                             // [B,NPOS,104] note_logits
  float* out4 = out3 + (size_t)B * NPOS * NOTE_CLS;   // [B,NPOS] note_pred

  char* ws = (char*)d_ws;
  double* dlog  = (double*)(ws + 0);                  // 768000 B
  float*  amean = (float*)(ws + 768000);              // 384000 B
  int*    segst = (int*)(ws + 1152000);               // 384128 B
  int*    nlen  = (int*)(ws + 1536128);               // 64 B
  float*  lmid  = (float*)(ws + 1536192);             // 416 B
  float*  ledge = (float*)(ws + 1536608);             // 416 B
  int*    preds = (int*)(ws + 1537024);               // 8 B
  float*  agg   = (float*)(ws + 1537536);             // 16*1024*256*4 = 16.78 MB

  k_dots<<<(B * T) / 4, 256, 0, stream>>>(feat, w_bd, b_bd, w_attn, b_attn, out0, dlog, amean);
  k_regulate<<<B, 256, 0, stream>>>(dlog, nonpad, out1, out2, segst, nlen);
  k_consts<<<1, 256, 0, stream>>>(conv_b, ln_g, ln_b, post_w, post_b, w_pitch, b_pitch, lmid, ledge, preds);
  k_seg<<<B * NSEG, 64, 0, stream>>>(feat, amean, segst, nlen, agg);
  k_conv_full<<<B * NT, 256, 0, stream>>>(agg, conv_w, conv_b, ln_g, ln_b, post_w, post_b,
                                          w_pitch, b_pitch, nlen, out3, out4);
  k_tail<<<B * NT, 256, 0, stream>>>(lmid, ledge, preds, nlen, out3, out4);
}

// Round 3
// 502.301 us; speedup vs baseline: 2.2663x; 1.0370x over previous
//
#include <hip/hip_runtime.h>
#include <math.h>

#define B 16
#define T 6000
#define H 256
#define NPOS 6001            // T+1 segments
#define NOTE_CLS 104
#define NOTE_NUM 100
#define NOTE_START 30
#define MIN_GAP 9
#define NSEG 1024            // cap on materialized segments (actual max len ~255)

#define T2 16                // conv tile (positions per block)
#define NT2 ((NPOS + T2 - 1) / T2)      // 376
#define XR2 20               // agg rows per tile: [t0-2, t0+17]
#define YR2 18               // y/u rows per tile: [t0-1, t0+16]

#define NWORDS 94            // ceil(T/64)
#define MAXRUNS 3088         // ceil(T/2) rounded up + pad for unroll-8

// ---------------- Kernel 1: bd + attn dot products (f64 accumulate) ----------
__global__ __launch_bounds__(256) void k_dots(
    const float* __restrict__ feat,
    const float* __restrict__ w_bd, const float* __restrict__ b_bd,
    const float* __restrict__ w_attn, const float* __restrict__ b_attn,
    float* __restrict__ out_logits, double* __restrict__ dlog,
    float* __restrict__ amean)
{
  int lane = threadIdx.x & 63, wv = threadIdx.x >> 6;
  int row = blockIdx.x * 4 + wv;                      // b*T + t
  if (row >= B * T) return;
  float4 f  = ((const float4*)(feat + (size_t)row * H))[lane];
  float4 wb = ((const float4*)w_bd)[lane];
  float4 wa = ((const float4*)w_attn)[lane];
  double sb = (double)f.x * wb.x + (double)f.y * wb.y + (double)f.z * wb.z + (double)f.w * wb.w;
  double sa = (double)f.x * wa.x + (double)f.y * wa.y + (double)f.z * wa.z + (double)f.w * wa.w;
  for (int off = 32; off; off >>= 1) { sb += __shfl_down(sb, off); sa += __shfl_down(sa, off); }
  if (lane == 0) {
    double lb = sb + (double)b_bd[0];
    lb = fmin(fmax(lb, -16.0), 16.0);
    out_logits[row] = (float)lb;
    dlog[row] = lb;
    double la = sa + (double)b_attn[0];
    amean[row] = (float)(1.0 / (1.0 + exp(-la)));
  }
}

// ---------------- Kernel 2: regulate_boundary (run-decomposed) ---------------
__global__ __launch_bounds__(256) void k_regulate(
    const double* __restrict__ dlog, const int* __restrict__ non_padding,
    float* __restrict__ out_bd, float* __restrict__ out_len,
    int* __restrict__ seg_start, int* __restrict__ note_len)
{
  __shared__ unsigned long long words[96];
  __shared__ unsigned long long smask[96];
  __shared__ int wcnt[96], woff[96];
  __shared__ int starts_s[MAXRUNS];
  __shared__ int besti_s[MAXRUNS];
  __shared__ int list_s[3072];
  __shared__ int red_i[4];
  __shared__ int R_s, lens_s, keep_s;

  int b = blockIdx.x, tid = threadIdx.x;
  int lane = tid & 63, wv = tid >> 6;
  const double* row = dlog + (size_t)b * T;

  for (int i = tid; i < MAXRUNS; i += 256) besti_s[i] = 0;

  // --- Phase A: bits -> words ---
  for (int c = 0; c < 24; ++c) {
    int t = c * 256 + tid;
    bool bit = (t < T) && (row[t] > 0.0);
    unsigned long long m = __ballot(bit ? 1 : 0);
    if (lane == 0) words[c * 4 + wv] = m;
  }
  __syncthreads();

  if (tid < NWORDS) {
    unsigned long long bits = words[tid];
    unsigned long long carry = (tid > 0) ? (words[tid - 1] >> 63) : 0ull;
    unsigned long long sm = bits & ~((bits << 1) | carry);
    smask[tid] = sm;
    wcnt[tid] = __popcll(sm);
  }
  __syncthreads();

  if (tid == 0) {
    int acc = 0;
    #pragma unroll 8
    for (int w = 0; w < NWORDS; ++w) { woff[w] = acc; acc += wcnt[w]; }
    R_s = acc;
  }
  __syncthreads();

  if (tid < NWORDS) {
    unsigned long long m = smask[tid];
    int off = woff[tid];
    int base = tid * 64;
    while (m) {
      int i = __builtin_ctzll(m);
      starts_s[off++] = base + i;
      m &= m - 1;
    }
  }
  __syncthreads();

  int R = R_s;
  int bd_last = (int)((words[(T - 1) >> 6] >> ((T - 1) & 63)) & 1ull);
  int Rc = R - (bd_last ? 1 : 0);          // only the trailing run can be unclosed

  // --- Phase B: per-run argmax walks ---
  for (int r = tid; r < R; r += 256) {
    int s = starts_s[r];
    double bv = row[s];
    int bi = s;
    for (int t = s + 1; t < T; ++t) {
      double d = row[t];
      if (!(d > 0.0)) break;
      if (d > bv) { bv = d; bi = t; }
    }
    besti_s[r] = bi;
  }

  // lens = sum(non_padding[b])
  int lens = 0;
  const int* npr = non_padding + (size_t)b * T;
  for (int t = tid; t < T; t += 256) lens += npr[t];
  for (int off = 32; off; off >>= 1) lens += __shfl_down(lens, off);
  if (lane == 0) red_i[wv] = lens;
  __syncthreads();
  if (tid == 0) lens_s = red_i[0] + red_i[1] + red_i[2] + red_i[3];
  __syncthreads();
  lens = lens_s;

  // --- Phase C: merge chain (thread 0), batched LDS loads ---
  if (tid == 0) {
    int cnt = 0, last = -1;
    for (int r0 = 0; r0 < Rc; r0 += 8) {
      int v[8];
      #pragma unroll
      for (int k = 0; k < 8; ++k) v[k] = besti_s[r0 + k];
      int kmax = Rc - r0; if (kmax > 8) kmax = 8;
      for (int k = 0; k < kmax; ++k) {
        int bi = v[k];
        bool merge = (last > 0) && (bi - last < MIN_GAP);
        int fi = bi;
        if (merge) { int s = bi + last; fi = (s + ((s >> 1) & 1)) >> 1; }  // half-to-even
        if (merge) list_s[cnt - 1] = fi;
        else       list_s[cnt++]   = fi;
        last = fi;
      }
    }
    // filter: res[0]=0 and res[t >= lens-1]=0
    int keep = 0;
    for (int i = 0; i < cnt; ++i) {
      int e = list_s[i];
      if (e != 0 && e < lens - 1) list_s[keep++] = e;
    }
    keep_s = keep;
  }
  __syncthreads();
  int keep = keep_s;

  // --- Phase D: outputs ---
  float* obd = out_bd + (size_t)b * T;
  for (int t = tid; t < T; t += 256) obd[t] = 0.f;
  __syncthreads();
  int* ss = seg_start + b * (T + 2);
  for (int i = tid; i < keep; i += 256) {
    int e = list_s[i];
    obd[e] = 1.f;
    ss[i + 1] = e;
  }
  if (tid == 0) {
    ss[0] = 0;
    ss[keep + 1] = T;
    note_len[b] = keep + 1;
    out_len[b] = (float)(keep + 1);
  }
}

// ---------------- Kernel 3: constant tail logits (zero-agg positions) --------
__global__ __launch_bounds__(256) void k_consts(
    const float* __restrict__ conv_b, const float* __restrict__ ln_g,
    const float* __restrict__ ln_b, const float* __restrict__ post_w,
    const float* __restrict__ post_b, const float* __restrict__ w_pitch,
    const float* __restrict__ b_pitch,
    float* __restrict__ lmid, float* __restrict__ ledge, int* __restrict__ preds)
{
  __shared__ float hc[H], zm[H], ze[H], red[8];
  __shared__ float lm[NOTE_CLS], le[NOTE_CLS];
  int tid = threadIdx.x, lane = tid & 63, wv = tid >> 6;
  float y = conv_b[tid];                        // conv of all-zero input
  float s = y;
  for (int off = 32; off; off >>= 1) s += __shfl_down(s, off);
  if (lane == 0) red[wv] = s;
  __syncthreads();
  float mean = (red[0] + red[1] + red[2] + red[3]) * (1.0f / H);
  float d = y - mean, q = d * d;
  for (int off = 32; off; off >>= 1) q += __shfl_down(q, off);
  if (lane == 0) red[4 + wv] = q;
  __syncthreads();
  float var = (red[4] + red[5] + red[6] + red[7]) * (1.0f / H);
  float h = d / sqrtf(var + 1e-5f) * ln_g[tid] + ln_b[tid];
  h = h > 0.f ? h : 0.01f * h;
  hc[tid] = h;
  __syncthreads();
  float am = 0.f, ae = 0.f;
  for (int cin = 0; cin < H; ++cin) {
    float hv = hc[cin];
    float p0 = post_w[(0 * H + cin) * H + tid];
    float p1 = post_w[(1 * H + cin) * H + tid];
    float p2 = post_w[(2 * H + cin) * H + tid];
    am += (p0 + p1 + p2) * hv;                  // interior position
    ae += (p0 + p1) * hv;                       // last position (right zero-pad)
  }
  zm[tid] = am + post_b[tid];
  ze[tid] = ae + post_b[tid];
  __syncthreads();
  if (tid < NOTE_CLS) {
    float sm = 0.f, se = 0.f;
    for (int c = 0; c < H; ++c) {
      float w = w_pitch[c * NOTE_CLS + tid];
      sm += zm[c] * w; se += ze[c] * w;
    }
    lm[tid] = sm + b_pitch[tid]; le[tid] = se + b_pitch[tid];
    lmid[tid] = lm[tid]; ledge[tid] = le[tid];
  }
  __syncthreads();
  if (tid == 0) {
    int bi = 0; float bv = lm[0];
    for (int p = 1; p < NOTE_CLS; ++p) if (lm[p] > bv) { bv = lm[p]; bi = p; }
    preds[0] = (bi > NOTE_NUM || bi < NOTE_START) ? 0 : bi;
    bi = 0; bv = le[0];
    for (int p = 1; p < NOTE_CLS; ++p) if (le[p] > bv) { bv = le[p]; bi = p; }
    preds[1] = (bi > NOTE_NUM || bi < NOTE_START) ? 0 : bi;
  }
}

// ---------------- Kernel 4: segment weighted means ---------------------------
__global__ __launch_bounds__(64) void k_seg(
    const float* __restrict__ feat, const float* __restrict__ amean,
    const int* __restrict__ seg_start, const int* __restrict__ note_len,
    float* __restrict__ agg)
{
  int blk = blockIdx.x;
  int b = blk / NSEG, n = blk - b * NSEG;
  int len = note_len[b];
  int lane = threadIdx.x;
  float4* o4 = (float4*)(agg + ((size_t)b * NSEG + n) * H);
  if (n >= len) {
    if (n < len + 40) o4[lane] = make_float4(0.f, 0.f, 0.f, 0.f);
    return;
  }
  int s = seg_start[b * (T + 2) + n];
  int e = seg_start[b * (T + 2) + n + 1];
  float4 acc = make_float4(0.f, 0.f, 0.f, 0.f);
  float dsum = 0.f;
  for (int t = s; t < e; ++t) {
    float am = amean[(size_t)b * T + t];
    float4 f = ((const float4*)(feat + ((size_t)b * T + t) * H))[lane];
    acc.x += am * f.x; acc.y += am * f.y; acc.z += am * f.z; acc.w += am * f.w;
    dsum += am;
  }
  float dn = dsum + 1e-5f;
  acc.x /= dn; acc.y /= dn; acc.z /= dn; acc.w /= dn;
  o4[lane] = acc;
}

// ---------------- Kernel 5 helpers: templated per position-group -------------
// PG 0: m 0-4 | PG 1: m 5-9 | PG 2: m 10-13 | PG 3: m 14-17   (y/u rows, YR2=18)
template<int PG> struct PGm {
  static constexpr int M0 = (PG < 2) ? PG * 5 : 10 + (PG - 2) * 4;
  static constexpr int MC = (PG < 2) ? 5 : 4;
};

template<int PG>
__device__ __forceinline__ void conv1_acc(
    const float* __restrict__ conv_w, const float* __restrict__ conv_b, int cout,
    const float (*xs)[XR2], float (&acc)[5], float (*rs)[4], float (*rq)[4],
    int lane, int wv4)
{
  constexpr int M0 = PGm<PG>::M0, MC = PGm<PG>::MC;
  #pragma unroll
  for (int j = 0; j < MC; ++j) acc[j] = 0.f;
  #pragma unroll 2
  for (int cin = 0; cin < H; ++cin) {
    float w0 = conv_w[(0 * H + cin) * H + cout];
    float w1 = conv_w[(1 * H + cin) * H + cout];
    float w2 = conv_w[(2 * H + cin) * H + cout];
    float xv[XR2];
    #pragma unroll
    for (int q = 0; q < XR2 / 4; ++q) {
      float4 t4 = *(const float4*)&xs[cin][4 * q];
      xv[4 * q] = t4.x; xv[4 * q + 1] = t4.y; xv[4 * q + 2] = t4.z; xv[4 * q + 3] = t4.w;
    }
    #pragma unroll
    for (int j = 0; j < MC; ++j)
      acc[j] += w0 * xv[M0 + j] + w1 * xv[M0 + j + 1] + w2 * xv[M0 + j + 2];
  }
  float cb = conv_b[cout];
  #pragma unroll
  for (int j = 0; j < MC; ++j) {
    acc[j] += cb;
    float s = acc[j], q = acc[j] * acc[j];
    for (int off = 32; off; off >>= 1) { s += __shfl_down(s, off); q += __shfl_down(q, off); }
    if (lane == 0) { rs[M0 + j][wv4] = s; rq[M0 + j][wv4] = q; }
  }
}

template<int PG>
__device__ __forceinline__ void u_phase(
    const float* __restrict__ ln_g, const float* __restrict__ ln_b, int cout, int t0,
    const float (*xs)[XR2], float (*us)[XR2], const float (&acc)[5],
    const float* sm, const float* sr)
{
  constexpr int M0 = PGm<PG>::M0, MC = PGm<PG>::MC;
  float g = ln_g[cout], bb = ln_b[cout];
  #pragma unroll
  for (int j = 0; j < MC; ++j) {
    int m = M0 + j;
    int p = t0 - 1 + m;
    float h = (acc[j] - sm[m]) * sr[m] * g + bb;
    h = h > 0.f ? h : 0.01f * h;
    float u = 0.f;
    if (p >= 0 && p < NPOS) u = xs[cout][m + 1] + h;   // xs row m+1 == agg[p]
    us[cout][m] = u;
  }
  if (PG == 3) { us[cout][18] = 0.f; us[cout][19] = 0.f; }
}

template<int PG>
__device__ __forceinline__ void conv2_z(
    const float* __restrict__ post_w, const float* __restrict__ post_b, int cout,
    const float (*us)[XR2], float (*zs)[XR2])
{
  constexpr int N0 = 4 * PG;
  float a2[4] = {0.f, 0.f, 0.f, 0.f};
  #pragma unroll 2
  for (int cin = 0; cin < H; ++cin) {
    float w0 = post_w[(0 * H + cin) * H + cout];
    float w1 = post_w[(1 * H + cin) * H + cout];
    float w2 = post_w[(2 * H + cin) * H + cout];
    float uv[XR2];
    #pragma unroll
    for (int q = 0; q < XR2 / 4; ++q) {
      float4 t4 = *(const float4*)&us[cin][4 * q];
      uv[4 * q] = t4.x; uv[4 * q + 1] = t4.y; uv[4 * q + 2] = t4.z; uv[4 * q + 3] = t4.w;
    }
    #pragma unroll
    for (int j = 0; j < 4; ++j)
      a2[j] += w0 * uv[N0 + j] + w1 * uv[N0 + j + 1] + w2 * uv[N0 + j + 2];
  }
  float pb = post_b[cout];
  #pragma unroll
  for (int j = 0; j < 4; ++j) zs[cout][N0 + j] = a2[j] + pb;
}

// ---------------- Kernel 5: conv -> LN -> leaky -> conv -> pitch -> argmax ---
__global__ __launch_bounds__(1024, 4) void k_conv_full(
    const float* __restrict__ agg,
    const float* __restrict__ conv_w, const float* __restrict__ conv_b,
    const float* __restrict__ ln_g, const float* __restrict__ ln_b,
    const float* __restrict__ post_w, const float* __restrict__ post_b,
    const float* __restrict__ w_pitch, const float* __restrict__ b_pitch,
    const int* __restrict__ note_len,
    float* __restrict__ out3, float* __restrict__ out4)
{
  int blk = blockIdx.x;
  int b = blk / NT2, tile = blk - b * NT2;
  int t0 = tile * T2;
  int len = note_len[b];
  if (t0 > len + 2) return;                      // tail kernel handles the rest

  __shared__ float xs[H][XR2];                   // agg rows, later z rows
  __shared__ float us[H][XR2];
  __shared__ float rs_[YR2][4], rq_[YR2][4];
  __shared__ float stat_mean[YR2], stat_rstd[YR2];

  int tid = threadIdx.x;
  int cout = tid & 255;
  int pg = tid >> 8;                             // 0..3, wave-uniform
  int lane = tid & 63;
  int wv4 = (tid >> 6) & 3;
  const float* aggb = agg + (size_t)b * NSEG * H;

  // load agg tile+halo: rows r = pg*5 .. pg*5+4  (p = t0-2+r)
  #pragma unroll
  for (int i = 0; i < 5; ++i) {
    int r = pg * 5 + i;
    int p = t0 - 2 + r;
    float v = 0.f;
    if (p >= 0 && p < NSEG) v = aggb[(size_t)p * H + cout];
    xs[cout][r] = v;
  }
  __syncthreads();

  float acc[5];
  switch (pg) {
    case 0: conv1_acc<0>(conv_w, conv_b, cout, xs, acc, rs_, rq_, lane, wv4); break;
    case 1: conv1_acc<1>(conv_w, conv_b, cout, xs, acc, rs_, rq_, lane, wv4); break;
    case 2: conv1_acc<2>(conv_w, conv_b, cout, xs, acc, rs_, rq_, lane, wv4); break;
    default: conv1_acc<3>(conv_w, conv_b, cout, xs, acc, rs_, rq_, lane, wv4); break;
  }
  __syncthreads();

  if (tid < YR2) {
    float S = rs_[tid][0] + rs_[tid][1] + rs_[tid][2] + rs_[tid][3];
    float Q = rq_[tid][0] + rq_[tid][1] + rq_[tid][2] + rq_[tid][3];
    float mean = S * (1.0f / H);
    float var = Q * (1.0f / H) - mean * mean;
    if (var < 0.f) var = 0.f;
    stat_mean[tid] = mean;
    stat_rstd[tid] = 1.0f / sqrtf(var + 1e-5f);
  }
  __syncthreads();

  switch (pg) {
    case 0: u_phase<0>(ln_g, ln_b, cout, t0, xs, us, acc, stat_mean, stat_rstd); break;
    case 1: u_phase<1>(ln_g, ln_b, cout, t0, xs, us, acc, stat_mean, stat_rstd); break;
    case 2: u_phase<2>(ln_g, ln_b, cout, t0, xs, us, acc, stat_mean, stat_rstd); break;
    default: u_phase<3>(ln_g, ln_b, cout, t0, xs, us, acc, stat_mean, stat_rstd); break;
  }
  __syncthreads();

  switch (pg) {                                  // writes z into xs
    case 0: conv2_z<0>(post_w, post_b, cout, us, xs); break;
    case 1: conv2_z<1>(post_w, post_b, cout, us, xs); break;
    case 2: conv2_z<2>(post_w, post_b, cout, us, xs); break;
    default: conv2_z<3>(post_w, post_b, cout, us, xs); break;
  }
  __syncthreads();

  // pitch head: one wave per position n = tid>>6; lanes 0..51 handle 2 classes
  {
    int n = tid >> 6;                            // 0..15
    float best = -1e30f; int bidx = 1 << 30;
    bool inb = (t0 + n) < NPOS;
    if (lane < 52) {
      float ax = 0.f, ay = 0.f;
      #pragma unroll 2
      for (int cin = 0; cin < H; ++cin) {
        float z = xs[cin][n];
        float2 w2 = *(const float2*)&w_pitch[cin * NOTE_CLS + 2 * lane];
        ax += z * w2.x; ay += z * w2.y;
      }
      float2 bp = *(const float2*)&b_pitch[2 * lane];
      ax += bp.x; ay += bp.y;
      if (inb) {
        float2 o; o.x = ax; o.y = ay;
        *(float2*)&out3[((size_t)b * NPOS + (t0 + n)) * NOTE_CLS + 2 * lane] = o;
      }
      best = ax; bidx = 2 * lane;
      if (ay > best) { best = ay; bidx = 2 * lane + 1; }
    }
    for (int off = 32; off; off >>= 1) {
      float bv2 = __shfl_down(best, off);
      int bi2 = __shfl_down(bidx, off);
      if (bv2 > best || (bv2 == best && bi2 < bidx)) { best = bv2; bidx = bi2; }
    }
    if (lane == 0 && inb) {
      int pred = (bidx > NOTE_NUM || bidx < NOTE_START) ? 0 : bidx;
      out4[(size_t)b * NPOS + t0 + n] = (float)pred;
    }
  }
}

// ---------------- Kernel 6: constant tail broadcast (16-tiles) ---------------
__global__ __launch_bounds__(256) void k_tail(
    const float* __restrict__ lmid, const float* __restrict__ ledge,
    const int* __restrict__ preds, const int* __restrict__ note_len,
    float* __restrict__ out3, float* __restrict__ out4)
{
  int blk = blockIdx.x;
  int b = blk / NT2, tile = blk - b * NT2;
  int t0 = tile * T2;
  int len = note_len[b];
  if (t0 <= len + 2) return;                    // handled by k_conv_full
  __shared__ float lm[NOTE_CLS], le[NOTE_CLS];
  int tid = threadIdx.x;
  if (tid < NOTE_CLS) { lm[tid] = lmid[tid]; le[tid] = ledge[tid]; }
  __syncthreads();
  int pm = preds[0], pe = preds[1];
  for (int i = tid; i < T2 * NOTE_CLS; i += 256) {
    int dn = i / NOTE_CLS;
    int n = t0 + dn, p = i - dn * NOTE_CLS;
    if (n >= NPOS) continue;
    out3[((size_t)b * NPOS + n) * NOTE_CLS + p] = (n == NPOS - 1) ? le[p] : lm[p];
  }
  if (tid < T2) {
    int n = t0 + tid;
    if (n < NPOS) out4[(size_t)b * NPOS + n] = (float)((n == NPOS - 1) ? pe : pm);
  }
}

// ---------------- launcher ---------------------------------------------------
extern "C" void kernel_launch(void* const* d_in, const int* in_sizes, int n_in,
                              void* d_out, int out_size, void* d_ws, size_t ws_size,
                              hipStream_t stream) {
  (void)in_sizes; (void)n_in; (void)out_size; (void)ws_size;
  const float* feat    = (const float*)d_in[0];
  const int*   nonpad  = (const int*)d_in[1];
  const float* w_bd    = (const float*)d_in[2];
  const float* b_bd    = (const float*)d_in[3];
  const float* w_attn  = (const float*)d_in[4];
  const float* b_attn  = (const float*)d_in[5];
  const float* conv_w  = (const float*)d_in[6];
  const float* conv_b  = (const float*)d_in[7];
  const float* ln_g    = (const float*)d_in[8];
  const float* ln_b    = (const float*)d_in[9];
  const float* post_w  = (const float*)d_in[10];
  const float* post_b  = (const float*)d_in[11];
  const float* w_pitch = (const float*)d_in[12];
  const float* b_pitch = (const float*)d_in[13];

  float* out  = (float*)d_out;
  float* out0 = out;                                  // [B,T] note_bd_logits
  float* out1 = out + (size_t)B * T;                  // [B,T] note_bd
  float* out2 = out + 2ull * B * T;                   // [B]   note_lengths
  float* out3 = out2 + B;                             // [B,NPOS,104] note_logits
  float* out4 = out3 + (size_t)B * NPOS * NOTE_CLS;   // [B,NPOS] note_pred

  char* ws = (char*)d_ws;
  double* dlog  = (double*)(ws + 0);                  // 768000 B
  float*  amean = (float*)(ws + 768000);              // 384000 B
  int*    segst = (int*)(ws + 1152000);               // 384128 B
  int*    nlen  = (int*)(ws + 1536128);               // 64 B
  float*  lmid  = (float*)(ws + 1536192);             // 416 B
  float*  ledge = (float*)(ws + 1536608);             // 416 B
  int*    preds = (int*)(ws + 1537024);               // 8 B
  float*  agg   = (float*)(ws + 1537536);             // 16*1024*256*4 = 16.78 MB

  k_dots<<<(B * T) / 4, 256, 0, stream>>>(feat, w_bd, b_bd, w_attn, b_attn, out0, dlog, amean);
  k_regulate<<<B, 256, 0, stream>>>(dlog, nonpad, out1, out2, segst, nlen);
  k_consts<<<1, 256, 0, stream>>>(conv_b, ln_g, ln_b, post_w, post_b, w_pitch, b_pitch, lmid, ledge, preds);
  k_seg<<<B * NSEG, 64, 0, stream>>>(feat, amean, segst, nlen, agg);
  k_conv_full<<<B * NT2, 1024, 0, stream>>>(agg, conv_w, conv_b, ln_g, ln_b, post_w, post_b,
                                            w_pitch, b_pitch, nlen, out3, out4);
  k_tail<<<B * NT2, 256, 0, stream>>>(lmid, ledge, preds, nlen, out3, out4);
}

// Round 4
// 452.672 us; speedup vs baseline: 2.5147x; 1.1096x over previous
//
#include <hip/hip_runtime.h>
#include <math.h>

#define B 16
#define T 6000
#define H 256
#define NPOS 6001            // T+1 segments
#define NOTE_CLS 104
#define NOTE_NUM 100
#define NOTE_START 30
#define MIN_GAP 9
#define NSEG 1024            // cap on materialized segments (actual max len ~255)

#define T2 16                // conv tile (positions per block)
#define NT2 ((NPOS + T2 - 1) / T2)      // 376
#define XSTR 28              // padded LDS row stride (floats, 16B-aligned, 8-way not 16-way)
#define ZSTR 260

#define NWORDS 94            // ceil(T/64)
#define MAXRUNS 3088

// ---------------- Kernel 1: bd + attn dot products (f64 accumulate) ----------
__global__ __launch_bounds__(256) void k_dots(
    const float* __restrict__ feat,
    const float* __restrict__ w_bd, const float* __restrict__ b_bd,
    const float* __restrict__ w_attn, const float* __restrict__ b_attn,
    float* __restrict__ out_logits, double* __restrict__ dlog,
    float* __restrict__ amean)
{
  int lane = threadIdx.x & 63, wv = threadIdx.x >> 6;
  int row = blockIdx.x * 4 + wv;                      // b*T + t
  if (row >= B * T) return;
  float4 f  = ((const float4*)(feat + (size_t)row * H))[lane];
  float4 wb = ((const float4*)w_bd)[lane];
  float4 wa = ((const float4*)w_attn)[lane];
  double sb = (double)f.x * wb.x + (double)f.y * wb.y + (double)f.z * wb.z + (double)f.w * wb.w;
  double sa = (double)f.x * wa.x + (double)f.y * wa.y + (double)f.z * wa.z + (double)f.w * wa.w;
  for (int off = 32; off; off >>= 1) { sb += __shfl_down(sb, off); sa += __shfl_down(sa, off); }
  if (lane == 0) {
    double lb = sb + (double)b_bd[0];
    lb = fmin(fmax(lb, -16.0), 16.0);
    out_logits[row] = (float)lb;
    dlog[row] = lb;
    double la = sa + (double)b_attn[0];
    amean[row] = (float)(1.0 / (1.0 + exp(-la)));
  }
}

// ---------------- Kernel 2: regulate_boundary (run-decomposed) ---------------
__global__ __launch_bounds__(256) void k_regulate(
    const double* __restrict__ dlog, const int* __restrict__ non_padding,
    float* __restrict__ out_bd, float* __restrict__ out_len,
    int* __restrict__ seg_start, int* __restrict__ note_len)
{
  __shared__ unsigned long long words[96];
  __shared__ unsigned long long smask[96];
  __shared__ int wcnt[96], woff[96];
  __shared__ int starts_s[MAXRUNS];
  __shared__ int besti_s[MAXRUNS];
  __shared__ int list_s[3072];
  __shared__ int red_i[4];
  __shared__ int R_s, lens_s, keep_s;

  int b = blockIdx.x, tid = threadIdx.x;
  int lane = tid & 63, wv = tid >> 6;
  const double* row = dlog + (size_t)b * T;

  for (int i = tid; i < MAXRUNS; i += 256) besti_s[i] = 0;

  // --- Phase A: bits -> words ---
  for (int c = 0; c < 24; ++c) {
    int t = c * 256 + tid;
    bool bit = (t < T) && (row[t] > 0.0);
    unsigned long long m = __ballot(bit ? 1 : 0);
    if (lane == 0) words[c * 4 + wv] = m;
  }
  __syncthreads();

  if (tid < NWORDS) {
    unsigned long long bits = words[tid];
    unsigned long long carry = (tid > 0) ? (words[tid - 1] >> 63) : 0ull;
    unsigned long long sm = bits & ~((bits << 1) | carry);
    smask[tid] = sm;
    wcnt[tid] = __popcll(sm);
  }
  __syncthreads();

  if (tid == 0) {
    int acc = 0;
    #pragma unroll 8
    for (int w = 0; w < NWORDS; ++w) { woff[w] = acc; acc += wcnt[w]; }
    R_s = acc;
  }
  __syncthreads();

  if (tid < NWORDS) {
    unsigned long long m = smask[tid];
    int off = woff[tid];
    int base = tid * 64;
    while (m) {
      int i = __builtin_ctzll(m);
      starts_s[off++] = base + i;
      m &= m - 1;
    }
  }
  __syncthreads();

  int R = R_s;
  int bd_last = (int)((words[(T - 1) >> 6] >> ((T - 1) & 63)) & 1ull);
  int Rc = R - (bd_last ? 1 : 0);

  // --- Phase B: per-run argmax walks ---
  for (int r = tid; r < R; r += 256) {
    int s = starts_s[r];
    double bv = row[s];
    int bi = s;
    for (int t = s + 1; t < T; ++t) {
      double d = row[t];
      if (!(d > 0.0)) break;
      if (d > bv) { bv = d; bi = t; }
    }
    besti_s[r] = bi;
  }

  // lens = sum(non_padding[b])
  int lens = 0;
  const int* npr = non_padding + (size_t)b * T;
  for (int t = tid; t < T; t += 256) lens += npr[t];
  for (int off = 32; off; off >>= 1) lens += __shfl_down(lens, off);
  if (lane == 0) red_i[wv] = lens;
  __syncthreads();
  if (tid == 0) lens_s = red_i[0] + red_i[1] + red_i[2] + red_i[3];
  __syncthreads();
  lens = lens_s;

  // --- Phase C: merge chain (thread 0), batched LDS loads ---
  if (tid == 0) {
    int cnt = 0, last = -1;
    for (int r0 = 0; r0 < Rc; r0 += 8) {
      int v[8];
      #pragma unroll
      for (int k = 0; k < 8; ++k) v[k] = besti_s[r0 + k];
      int kmax = Rc - r0; if (kmax > 8) kmax = 8;
      for (int k = 0; k < kmax; ++k) {
        int bi = v[k];
        bool merge = (last > 0) && (bi - last < MIN_GAP);
        int fi = bi;
        if (merge) { int s = bi + last; fi = (s + ((s >> 1) & 1)) >> 1; }  // half-to-even
        if (merge) list_s[cnt - 1] = fi;
        else       list_s[cnt++]   = fi;
        last = fi;
      }
    }
    int keep = 0;
    for (int i = 0; i < cnt; ++i) {
      int e = list_s[i];
      if (e != 0 && e < lens - 1) list_s[keep++] = e;
    }
    keep_s = keep;
  }
  __syncthreads();
  int keep = keep_s;

  // --- Phase D: outputs ---
  float* obd = out_bd + (size_t)b * T;
  for (int t = tid; t < T; t += 256) obd[t] = 0.f;
  __syncthreads();
  int* ss = seg_start + b * (T + 2);
  for (int i = tid; i < keep; i += 256) {
    int e = list_s[i];
    obd[e] = 1.f;
    ss[i + 1] = e;
  }
  if (tid == 0) {
    ss[0] = 0;
    ss[keep + 1] = T;
    note_len[b] = keep + 1;
    out_len[b] = (float)(keep + 1);
  }
}

// ---------------- Kernel 3: constant tail logits (zero-agg positions) --------
__global__ __launch_bounds__(256) void k_consts(
    const float* __restrict__ conv_b, const float* __restrict__ ln_g,
    const float* __restrict__ ln_b, const float* __restrict__ post_w,
    const float* __restrict__ post_b, const float* __restrict__ w_pitch,
    const float* __restrict__ b_pitch,
    float* __restrict__ lmid, float* __restrict__ ledge, int* __restrict__ preds)
{
  __shared__ float hc[H], zm[H], ze[H], red[8];
  __shared__ float lm[NOTE_CLS], le[NOTE_CLS];
  int tid = threadIdx.x, lane = tid & 63, wv = tid >> 6;
  float y = conv_b[tid];                        // conv of all-zero input
  float s = y;
  for (int off = 32; off; off >>= 1) s += __shfl_down(s, off);
  if (lane == 0) red[wv] = s;
  __syncthreads();
  float mean = (red[0] + red[1] + red[2] + red[3]) * (1.0f / H);
  float d = y - mean, q = d * d;
  for (int off = 32; off; off >>= 1) q += __shfl_down(q, off);
  if (lane == 0) red[4 + wv] = q;
  __syncthreads();
  float var = (red[4] + red[5] + red[6] + red[7]) * (1.0f / H);
  float h = d / sqrtf(var + 1e-5f) * ln_g[tid] + ln_b[tid];
  h = h > 0.f ? h : 0.01f * h;
  hc[tid] = h;
  __syncthreads();
  float am = 0.f, ae = 0.f;
  for (int cin = 0; cin < H; ++cin) {
    float hv = hc[cin];
    float p0 = post_w[(0 * H + cin) * H + tid];
    float p1 = post_w[(1 * H + cin) * H + tid];
    float p2 = post_w[(2 * H + cin) * H + tid];
    am += (p0 + p1 + p2) * hv;
    ae += (p0 + p1) * hv;
  }
  zm[tid] = am + post_b[tid];
  ze[tid] = ae + post_b[tid];
  __syncthreads();
  if (tid < NOTE_CLS) {
    float sm = 0.f, se = 0.f;
    for (int c = 0; c < H; ++c) {
      float w = w_pitch[c * NOTE_CLS + tid];
      sm += zm[c] * w; se += ze[c] * w;
    }
    lm[tid] = sm + b_pitch[tid]; le[tid] = se + b_pitch[tid];
    lmid[tid] = lm[tid]; ledge[tid] = le[tid];
  }
  __syncthreads();
  if (tid == 0) {
    int bi = 0; float bv = lm[0];
    for (int p = 1; p < NOTE_CLS; ++p) if (lm[p] > bv) { bv = lm[p]; bi = p; }
    preds[0] = (bi > NOTE_NUM || bi < NOTE_START) ? 0 : bi;
    bi = 0; bv = le[0];
    for (int p = 1; p < NOTE_CLS; ++p) if (le[p] > bv) { bv = le[p]; bi = p; }
    preds[1] = (bi > NOTE_NUM || bi < NOTE_START) ? 0 : bi;
  }
}

// ---------------- Kernel 4: segment weighted means ---------------------------
__global__ __launch_bounds__(64) void k_seg(
    const float* __restrict__ feat, const float* __restrict__ amean,
    const int* __restrict__ seg_start, const int* __restrict__ note_len,
    float* __restrict__ agg)
{
  int blk = blockIdx.x;
  int b = blk / NSEG, n = blk - b * NSEG;
  int len = note_len[b];
  int lane = threadIdx.x;
  float4* o4 = (float4*)(agg + ((size_t)b * NSEG + n) * H);
  if (n >= len) {
    if (n < len + 40) o4[lane] = make_float4(0.f, 0.f, 0.f, 0.f);
    return;
  }
  int s = seg_start[b * (T + 2) + n];
  int e = seg_start[b * (T + 2) + n + 1];
  float4 acc = make_float4(0.f, 0.f, 0.f, 0.f);
  float dsum = 0.f;
  for (int t = s; t < e; ++t) {
    float am = amean[(size_t)b * T + t];
    float4 f = ((const float4*)(feat + ((size_t)b * T + t) * H))[lane];
    acc.x += am * f.x; acc.y += am * f.y; acc.z += am * f.z; acc.w += am * f.w;
    dsum += am;
  }
  float dn = dsum + 1e-5f;
  acc.x /= dn; acc.y /= dn; acc.z /= dn; acc.w /= dn;
  o4[lane] = acc;
}

// ---------------- Kernel 5 helpers (PG = position half, TM=9/8, static idx) --
// conv1: y rows m = PG*9 + j, j=0..8 ; window floats xs[cin][XB .. XB+11]
template<int PG>
__device__ __forceinline__ void conv1_t(
    const float* __restrict__ cw, const float* __restrict__ cb, int cout,
    const float (*xs)[XSTR], float (&acc)[9], float (*rs)[4], float (*rq)[4],
    int lane, int wv4)
{
  constexpr int XB = PG ? 8 : 0;
  constexpr int S  = PG ? 1 : 0;
  #pragma unroll
  for (int j = 0; j < 9; ++j) acc[j] = 0.f;
  #pragma unroll 2
  for (int cin = 0; cin < H; ++cin) {
    float w0 = cw[cin * H + cout];
    float w1 = cw[(H + cin) * H + cout];
    float w2 = cw[(2 * H + cin) * H + cout];
    float4 a = *(const float4*)&xs[cin][XB];
    float4 bq = *(const float4*)&xs[cin][XB + 4];
    float4 c = *(const float4*)&xs[cin][XB + 8];
    float L[12] = { a.x, a.y, a.z, a.w, bq.x, bq.y, bq.z, bq.w, c.x, c.y, c.z, c.w };
    #pragma unroll
    for (int j = 0; j < 9; ++j)
      acc[j] += w0 * L[j + S] + w1 * L[j + S + 1] + w2 * L[j + S + 2];
  }
  float cbv = cb[cout];
  #pragma unroll
  for (int j = 0; j < 9; ++j) {
    acc[j] += cbv;
    float s = acc[j], q = acc[j] * acc[j];
    for (int off = 32; off; off >>= 1) { s += __shfl_down(s, off); q += __shfl_down(q, off); }
    if (lane == 0) { rs[PG * 9 + j][wv4] = s; rq[PG * 9 + j][wv4] = q; }
  }
}

template<int PG>
__device__ __forceinline__ void u_t(
    const float* __restrict__ g_, const float* __restrict__ b_, int cout, int t0,
    const float (*xs)[XSTR], float (*us)[XSTR], const float (&acc)[9],
    const float* sm, const float* sr)
{
  float g = g_[cout], bb = b_[cout];
  #pragma unroll
  for (int j = 0; j < 9; ++j) {
    int m = PG * 9 + j;
    int p = t0 - 1 + m;
    float h = (acc[j] - sm[m]) * sr[m] * g + bb;
    h = h > 0.f ? h : 0.01f * h;
    us[cout][m] = (p >= 0 && p < NPOS) ? xs[cout][m + 1] + h : 0.f;
  }
  if (PG == 1) { us[cout][18] = 0.f; us[cout][19] = 0.f; }
}

// conv2: z rows n = PG*8 + j, j=0..7 ; window floats us[cin][XB2 .. XB2+11]
template<int PG>
__device__ __forceinline__ void conv2_t(
    const float* __restrict__ pw, const float* __restrict__ pb, int cout,
    const float (*us)[XSTR], float* zt)
{
  constexpr int XB2 = PG ? 8 : 0;
  float a2[8];
  #pragma unroll
  for (int j = 0; j < 8; ++j) a2[j] = 0.f;
  #pragma unroll 2
  for (int cin = 0; cin < H; ++cin) {
    float w0 = pw[cin * H + cout];
    float w1 = pw[(H + cin) * H + cout];
    float w2 = pw[(2 * H + cin) * H + cout];
    float4 a = *(const float4*)&us[cin][XB2];
    float4 bq = *(const float4*)&us[cin][XB2 + 4];
    float4 c = *(const float4*)&us[cin][XB2 + 8];
    float L[12] = { a.x, a.y, a.z, a.w, bq.x, bq.y, bq.z, bq.w, c.x, c.y, c.z, c.w };
    #pragma unroll
    for (int j = 0; j < 8; ++j)
      a2[j] += w0 * L[j] + w1 * L[j + 1] + w2 * L[j + 2];
  }
  float pbv = pb[cout];
  #pragma unroll
  for (int j = 0; j < 8; ++j) zt[(PG * 8 + j) * ZSTR + cout] = a2[j] + pbv;
}

// ---------------- Kernel 5: conv -> LN -> leaky -> conv -> pitch -> argmax ---
__global__ __launch_bounds__(512) void k_conv_full(
    const float* __restrict__ agg,
    const float* __restrict__ conv_w, const float* __restrict__ conv_b,
    const float* __restrict__ ln_g, const float* __restrict__ ln_b,
    const float* __restrict__ post_w, const float* __restrict__ post_b,
    const float* __restrict__ w_pitch, const float* __restrict__ b_pitch,
    const int* __restrict__ note_len,
    float* __restrict__ out3, float* __restrict__ out4)
{
  int blk = blockIdx.x;
  int b = blk / NT2, tile = blk - b * NT2;
  int t0 = tile * T2;
  int len = note_len[b];
  if (t0 > len + 2) return;                      // tail kernel handles the rest

  __shared__ float xs[H][XSTR];                  // agg rows (20 used)
  __shared__ float us[H][XSTR];                  // u rows (18 used + 2 zero)
  __shared__ float zt[T2 * ZSTR];                // z transposed [n][cout]
  __shared__ float rs_[18][4], rq_[18][4];
  __shared__ float stat_mean[18], stat_rstd[18];
  __shared__ float pvs[T2][26];
  __shared__ int   pis[T2][26];

  int tid = threadIdx.x;
  int cout = tid & 255;
  int pg = tid >> 8;                             // 0..1, wave-uniform
  int lane = tid & 63;
  int wv4 = (tid >> 6) & 3;
  const float* aggb = agg + (size_t)b * NSEG * H;

  // stage agg rows r=0..19 (p = t0-2+r); pg0 loads r 0..9, pg1 r 10..19
  #pragma unroll
  for (int i = 0; i < 10; ++i) {
    int r = pg * 10 + i;
    int p = t0 - 2 + r;
    float v = 0.f;
    if (p >= 0 && p < NSEG) v = aggb[(size_t)p * H + cout];
    xs[cout][r] = v;
  }
  __syncthreads();

  float acc[9];
  if (pg == 0) conv1_t<0>(conv_w, conv_b, cout, xs, acc, rs_, rq_, lane, wv4);
  else         conv1_t<1>(conv_w, conv_b, cout, xs, acc, rs_, rq_, lane, wv4);
  __syncthreads();

  if (tid < 18) {
    float S = rs_[tid][0] + rs_[tid][1] + rs_[tid][2] + rs_[tid][3];
    float Q = rq_[tid][0] + rq_[tid][1] + rq_[tid][2] + rq_[tid][3];
    float mean = S * (1.0f / H);
    float var = Q * (1.0f / H) - mean * mean;
    if (var < 0.f) var = 0.f;
    stat_mean[tid] = mean;
    stat_rstd[tid] = 1.0f / sqrtf(var + 1e-5f);
  }
  __syncthreads();

  if (pg == 0) u_t<0>(ln_g, ln_b, cout, t0, xs, us, acc, stat_mean, stat_rstd);
  else         u_t<1>(ln_g, ln_b, cout, t0, xs, us, acc, stat_mean, stat_rstd);
  __syncthreads();

  if (pg == 0) conv2_t<0>(post_w, post_b, cout, us, zt);
  else         conv2_t<1>(post_w, post_b, cout, us, zt);
  __syncthreads();

  // pitch head: 208 threads = 8 n-groups x 26 class-quads; 2 positions each
  if (tid < 208) {
    int n8 = tid / 26, c26 = tid - n8 * 26;
    float4 a0 = make_float4(0.f, 0.f, 0.f, 0.f), a1 = a0;
    const float* z0 = &zt[n8 * ZSTR];
    const float* z1 = &zt[(n8 + 8) * ZSTR];
    #pragma unroll 2
    for (int cin = 0; cin < H; ++cin) {
      float4 w4 = *(const float4*)&w_pitch[cin * NOTE_CLS + 4 * c26];
      float zv0 = z0[cin], zv1 = z1[cin];
      a0.x += zv0 * w4.x; a0.y += zv0 * w4.y; a0.z += zv0 * w4.z; a0.w += zv0 * w4.w;
      a1.x += zv1 * w4.x; a1.y += zv1 * w4.y; a1.z += zv1 * w4.z; a1.w += zv1 * w4.w;
    }
    float4 bp = *(const float4*)&b_pitch[4 * c26];
    a0.x += bp.x; a0.y += bp.y; a0.z += bp.z; a0.w += bp.w;
    a1.x += bp.x; a1.y += bp.y; a1.z += bp.z; a1.w += bp.w;
    #pragma unroll
    for (int r = 0; r < 2; ++r) {
      int n = n8 + 8 * r;
      float4 o = r ? a1 : a0;
      if (t0 + n < NPOS)
        *(float4*)&out3[((size_t)b * NPOS + (t0 + n)) * NOTE_CLS + 4 * c26] = o;
      float bv = o.x; int bi = 4 * c26;
      if (o.y > bv) { bv = o.y; bi = 4 * c26 + 1; }
      if (o.z > bv) { bv = o.z; bi = 4 * c26 + 2; }
      if (o.w > bv) { bv = o.w; bi = 4 * c26 + 3; }
      pvs[n][c26] = bv; pis[n][c26] = bi;
    }
  }
  __syncthreads();
  if (tid < T2 && t0 + tid < NPOS) {
    float bv = pvs[tid][0]; int bi = pis[tid][0];
    #pragma unroll 1
    for (int k = 1; k < 26; ++k)
      if (pvs[tid][k] > bv) { bv = pvs[tid][k]; bi = pis[tid][k]; }
    int pred = (bi > NOTE_NUM || bi < NOTE_START) ? 0 : bi;
    out4[(size_t)b * NPOS + t0 + tid] = (float)pred;
  }
}

// ---------------- Kernel 6: constant tail broadcast (16-tiles) ---------------
__global__ __launch_bounds__(256) void k_tail(
    const float* __restrict__ lmid, const float* __restrict__ ledge,
    const int* __restrict__ preds, const int* __restrict__ note_len,
    float* __restrict__ out3, float* __restrict__ out4)
{
  int blk = blockIdx.x;
  int b = blk / NT2, tile = blk - b * NT2;
  int t0 = tile * T2;
  int len = note_len[b];
  if (t0 <= len + 2) return;                    // handled by k_conv_full
  __shared__ float lm[NOTE_CLS], le[NOTE_CLS];
  int tid = threadIdx.x;
  if (tid < NOTE_CLS) { lm[tid] = lmid[tid]; le[tid] = ledge[tid]; }
  __syncthreads();
  int pm = preds[0], pe = preds[1];
  for (int i = tid; i < T2 * NOTE_CLS; i += 256) {
    int dn = i / NOTE_CLS;
    int n = t0 + dn, p = i - dn * NOTE_CLS;
    if (n >= NPOS) continue;
    out3[((size_t)b * NPOS + n) * NOTE_CLS + p] = (n == NPOS - 1) ? le[p] : lm[p];
  }
  if (tid < T2) {
    int n = t0 + tid;
    if (n < NPOS) out4[(size_t)b * NPOS + n] = (float)((n == NPOS - 1) ? pe : pm);
  }
}

// ---------------- launcher ---------------------------------------------------
extern "C" void kernel_launch(void* const* d_in, const int* in_sizes, int n_in,
                              void* d_out, int out_size, void* d_ws, size_t ws_size,
                              hipStream_t stream) {
  (void)in_sizes; (void)n_in; (void)out_size; (void)ws_size;
  const float* feat    = (const float*)d_in[0];
  const int*   nonpad  = (const int*)d_in[1];
  const float* w_bd    = (const float*)d_in[2];
  const float* b_bd    = (const float*)d_in[3];
  const float* w_attn  = (const float*)d_in[4];
  const float* b_attn  = (const float*)d_in[5];
  const float* conv_w  = (const float*)d_in[6];
  const float* conv_b  = (const float*)d_in[7];
  const float* ln_g    = (const float*)d_in[8];
  const float* ln_b    = (const float*)d_in[9];
  const float* post_w  = (const float*)d_in[10];
  const float* post_b  = (const float*)d_in[11];
  const float* w_pitch = (const float*)d_in[12];
  const float* b_pitch = (const float*)d_in[13];

  float* out  = (float*)d_out;
  float* out0 = out;                                  // [B,T] note_bd_logits
  float* out1 = out + (size_t)B * T;                  // [B,T] note_bd
  float* out2 = out + 2ull * B * T;                   // [B]   note_lengths
  float* out3 = out2 + B;                             // [B,NPOS,104] note_logits
  float* out4 = out3 + (size_t)B * NPOS * NOTE_CLS;   // [B,NPOS] note_pred

  char* ws = (char*)d_ws;
  double* dlog  = (double*)(ws + 0);                  // 768000 B
  float*  amean = (float*)(ws + 768000);              // 384000 B
  int*    segst = (int*)(ws + 1152000);               // 384128 B
  int*    nlen  = (int*)(ws + 1536128);               // 64 B
  float*  lmid  = (float*)(ws + 1536192);             // 416 B
  float*  ledge = (float*)(ws + 1536608);             // 416 B
  int*    preds = (int*)(ws + 1537024);               // 8 B
  float*  agg   = (float*)(ws + 1537536);             // 16*1024*256*4 = 16.78 MB

  k_dots<<<(B * T) / 4, 256, 0, stream>>>(feat, w_bd, b_bd, w_attn, b_attn, out0, dlog, amean);
  k_regulate<<<B, 256, 0, stream>>>(dlog, nonpad, out1, out2, segst, nlen);
  k_consts<<<1, 256, 0, stream>>>(conv_b, ln_g, ln_b, post_w, post_b, w_pitch, b_pitch, lmid, ledge, preds);
  k_seg<<<B * NSEG, 64, 0, stream>>>(feat, amean, segst, nlen, agg);
  k_conv_full<<<B * NT2, 512, 0, stream>>>(agg, conv_w, conv_b, ln_g, ln_b, post_w, post_b,
                                           w_pitch, b_pitch, nlen, out3, out4);
  k_tail<<<B * NT2, 256, 0, stream>>>(lmid, ledge, preds, nlen, out3, out4);
}

// Round 5
// 320.497 us; speedup vs baseline: 3.5518x; 1.4124x over previous
//
#include <hip/hip_runtime.h>
#include <math.h>

#define B 16
#define T 6000
#define H 256
#define NPOS 6001            // T+1 segments
#define NOTE_CLS 104
#define NOTE_NUM 100
#define NOTE_START 30
#define MIN_GAP 9
#define NSEG 1024            // cap on materialized segments (actual max len ~255)

#define T2 16                // conv tile (positions per block)
#define NT2 ((NPOS + T2 - 1) / T2)      // 376
#define XSTR 28              // padded LDS row stride (floats, 16B-aligned, 8-way not 16-way)
#define ZSTR 260

#define NWORDS 94            // ceil(T/64)
#define MAXRUNS 3088

// ---------------- Kernel 1: bd + attn dot products (f64 accumulate) ----------
__global__ __launch_bounds__(256) void k_dots(
    const float* __restrict__ feat,
    const float* __restrict__ w_bd, const float* __restrict__ b_bd,
    const float* __restrict__ w_attn, const float* __restrict__ b_attn,
    float* __restrict__ out_logits, double* __restrict__ dlog,
    float* __restrict__ amean)
{
  int lane = threadIdx.x & 63, wv = threadIdx.x >> 6;
  int row = blockIdx.x * 4 + wv;                      // b*T + t
  if (row >= B * T) return;
  float4 f  = ((const float4*)(feat + (size_t)row * H))[lane];
  float4 wb = ((const float4*)w_bd)[lane];
  float4 wa = ((const float4*)w_attn)[lane];
  double sb = (double)f.x * wb.x + (double)f.y * wb.y + (double)f.z * wb.z + (double)f.w * wb.w;
  double sa = (double)f.x * wa.x + (double)f.y * wa.y + (double)f.z * wa.z + (double)f.w * wa.w;
  for (int off = 32; off; off >>= 1) { sb += __shfl_down(sb, off); sa += __shfl_down(sa, off); }
  if (lane == 0) {
    double lb = sb + (double)b_bd[0];
    lb = fmin(fmax(lb, -16.0), 16.0);
    out_logits[row] = (float)lb;
    dlog[row] = lb;
    double la = sa + (double)b_attn[0];
    amean[row] = (float)(1.0 / (1.0 + exp(-la)));
  }
}

// ---------------- block-wide exclusive scan helper (in-place), n uniform -----
__device__ __forceinline__ int block_scan_excl(int* a, int n, int tid, int lane,
                                               int wv, int* wsums)
{
  int base = 0;
  for (int c0 = 0; c0 < n; c0 += 256) {
    int i = c0 + tid;
    int v = (i < n) ? a[i] : 0;
    int s = v;
    #pragma unroll
    for (int off = 1; off < 64; off <<= 1) {
      int t = __shfl_up(s, off);
      if (lane >= off) s += t;
    }
    if (lane == 63) wsums[wv] = s;
    __syncthreads();
    int wbase = 0;
    for (int w = 0; w < wv; ++w) wbase += wsums[w];
    int ctot = wsums[0] + wsums[1] + wsums[2] + wsums[3];
    if (i < n) a[i] = base + wbase + s - v;    // exclusive
    base += ctot;
    __syncthreads();
  }
  return base;
}

// ---------------- Kernel 2: regulate_boundary (cluster-parallel chain) -------
__global__ __launch_bounds__(256) void k_regulate(
    const double* __restrict__ dlog, const int* __restrict__ non_padding,
    float* __restrict__ out_bd, float* __restrict__ out_len,
    int* __restrict__ seg_start, int* __restrict__ note_len)
{
  __shared__ double row_s[T];                    // 48000 B
  __shared__ unsigned long long words[96];
  __shared__ unsigned long long smask[NWORDS], emask[NWORDS];
  __shared__ int wcnt[NWORDS], woff[NWORDS], ecnt[NWORDS], eoff[NWORDS];
  __shared__ int starts_s[MAXRUNS];              // later reused as list_s
  __shared__ int ends_s[MAXRUNS];                // later reused as filter flags
  __shared__ int besti_s[MAXRUNS];               // later holds kept values
  __shared__ int cstart_s[MAXRUNS + 1];
  __shared__ int kofs_s[MAXRUNS];
  __shared__ unsigned long long cmask[52];
  __shared__ int ccnt[52], coff[52];
  __shared__ int wsums[4], red_i[4];
  __shared__ int R_s, NC_s, lens_s;

  int b = blockIdx.x, tid = threadIdx.x;
  int lane = tid & 63, wv = tid >> 6;
  const double* row = dlog + (size_t)b * T;

  // --- Phase A: stage row in LDS + bit words ---
  for (int c = 0; c < 24; ++c) {
    int t = c * 256 + tid;
    double d = (t < T) ? row[t] : -1.0;
    if (t < T) row_s[t] = d;
    unsigned long long m = __ballot((t < T) && (d > 0.0));
    if (lane == 0) words[c * 4 + wv] = m;
  }
  __syncthreads();

  // start/end masks: start = 0->1, end = position of 0 after a 1
  if (tid < NWORDS) {
    unsigned long long bits = words[tid];
    unsigned long long carry = (tid > 0) ? (words[tid - 1] >> 63) : 0ull;
    unsigned long long pm = (bits << 1) | carry;
    unsigned long long sm = bits & ~pm;
    unsigned long long em = (~bits) & pm;
    smask[tid] = sm;  emask[tid] = em;
    wcnt[tid] = __popcll(sm);  ecnt[tid] = __popcll(em);
  }
  __syncthreads();

  if (tid == 0) {
    int a = 0, e = 0;
    #pragma unroll 8
    for (int w = 0; w < NWORDS; ++w) {
      woff[w] = a; a += wcnt[w];
      eoff[w] = e; e += ecnt[w];
    }
    R_s = a;
  }
  __syncthreads();

  if (tid < NWORDS) {
    unsigned long long m = smask[tid];
    int off = woff[tid], base = tid * 64;
    while (m) { int i = __builtin_ctzll(m); starts_s[off++] = base + i; m &= m - 1; }
    m = emask[tid]; off = eoff[tid];
    while (m) { int i = __builtin_ctzll(m); ends_s[off++] = base + i; m &= m - 1; }
  }

  // lens = sum(non_padding[b]) (overlap with compaction)
  {
    int lens = 0;
    const int* npr = non_padding + (size_t)b * T;
    for (int t = tid; t < T; t += 256) lens += npr[t];
    for (int off = 32; off; off >>= 1) lens += __shfl_down(lens, off);
    if (lane == 0) red_i[wv] = lens;
  }
  __syncthreads();
  if (tid == 0) lens_s = red_i[0] + red_i[1] + red_i[2] + red_i[3];

  int R = R_s;
  int bd_last = (int)((words[(T - 1) >> 6] >> ((T - 1) & 63)) & 1ull);
  int Rc = R - (bd_last ? 1 : 0);          // trailing unclosed run excluded

  // --- Phase B: per-run argmax (break-free, LDS reads) ---
  for (int r = tid; r < R; r += 256) {
    int s = starts_s[r], e = ends_s[r];
    double bv = row_s[s];
    int bi = s;
    for (int t = s + 1; t < e; ++t) {
      double d = row_s[t];
      if (d > bv) { bv = d; bi = t; }
    }
    besti_s[r] = bi;
  }
  __syncthreads();

  // --- cluster boundaries: flag[r] = (r==0) || (bi[r]-bi[r-1] >= MIN_GAP) ---
  int NRW = (Rc + 63) >> 6;
  for (int c0 = 0; c0 < NRW * 64; c0 += 256) {
    int r = c0 + tid;
    bool fl = false;
    if (r < Rc) fl = (r == 0) || (besti_s[r] - besti_s[r - 1] >= MIN_GAP);
    unsigned long long m = __ballot(fl);
    int widx = (c0 >> 6) + wv;
    if (lane == 0 && widx < 52) cmask[widx] = m;
  }
  __syncthreads();
  if (tid < NRW) ccnt[tid] = __popcll(cmask[tid]);
  __syncthreads();
  if (tid == 0) {
    int a = 0;
    for (int w = 0; w < NRW; ++w) { coff[w] = a; a += ccnt[w]; }
    NC_s = a;
  }
  __syncthreads();
  if (tid < NRW) {
    unsigned long long m = cmask[tid];
    int off = coff[tid], base = tid * 64;
    while (m) { int i = __builtin_ctzll(m); cstart_s[off++] = base + i; m &= m - 1; }
  }
  __syncthreads();
  int NC = NC_s;
  if (tid == 0) cstart_s[NC] = Rc;
  __syncthreads();

  // --- Phase C: per-cluster merge chains (parallel, in-place kept lists) ---
  for (int j = tid; j < NC; j += 256) {
    int r0 = cstart_s[j], r1 = cstart_s[j + 1];
    int last = -1, kc = 0;
    for (int r = r0; r < r1; ++r) {
      int bi = besti_s[r];
      bool merge = (last > 0) && (bi - last < MIN_GAP);
      int fi = bi;
      if (merge) { int sm2 = bi + last; fi = (sm2 + ((sm2 >> 1) & 1)) >> 1; }  // half-to-even
      if (merge) besti_s[r0 + kc - 1] = fi;
      else       besti_s[r0 + kc++]   = fi;
      last = fi;
    }
    kofs_s[j] = kc;
  }
  __syncthreads();

  // --- concat: exclusive scan of kept counts, compact into list (starts_s) ---
  int K = block_scan_excl(kofs_s, NC, tid, lane, wv, wsums);
  __syncthreads();
  for (int j = tid; j < NC; j += 256) {
    int off = kofs_s[j];
    int cnt = ((j + 1 < NC) ? kofs_s[j + 1] : K) - off;
    int src = cstart_s[j];
    for (int k = 0; k < cnt; ++k) starts_s[off + k] = besti_s[src + k];
  }
  __syncthreads();

  // --- filter (e!=0 && e<lens-1) + compaction scan ---
  int lens = lens_s;
  for (int i = tid; i < K; i += 256) {
    int e = starts_s[i];
    ends_s[i] = (e != 0 && e < lens - 1) ? 1 : 0;
  }
  __syncthreads();
  int keep = block_scan_excl(ends_s, K, tid, lane, wv, wsums);

  // --- outputs ---
  float* obd = out_bd + (size_t)b * T;
  for (int t = tid; t < T; t += 256) obd[t] = 0.f;
  __syncthreads();
  int* ss = seg_start + b * (T + 2);
  for (int i = tid; i < K; i += 256) {
    int e = starts_s[i];
    if (e != 0 && e < lens - 1) {
      int pos = ends_s[i];
      ss[pos + 1] = e;
      obd[e] = 1.f;
    }
  }
  if (tid == 0) {
    ss[0] = 0;
    ss[keep + 1] = T;
    note_len[b] = keep + 1;
    out_len[b] = (float)(keep + 1);
  }
}

// ---------------- Kernel 3: constant tail logits (zero-agg positions) --------
__global__ __launch_bounds__(256) void k_consts(
    const float* __restrict__ conv_b, const float* __restrict__ ln_g,
    const float* __restrict__ ln_b, const float* __restrict__ post_w,
    const float* __restrict__ post_b, const float* __restrict__ w_pitch,
    const float* __restrict__ b_pitch,
    float* __restrict__ lmid, float* __restrict__ ledge, int* __restrict__ preds)
{
  __shared__ float hc[H], zm[H], ze[H], red[8];
  __shared__ float lm[NOTE_CLS], le[NOTE_CLS];
  int tid = threadIdx.x, lane = tid & 63, wv = tid >> 6;
  float y = conv_b[tid];                        // conv of all-zero input
  float s = y;
  for (int off = 32; off; off >>= 1) s += __shfl_down(s, off);
  if (lane == 0) red[wv] = s;
  __syncthreads();
  float mean = (red[0] + red[1] + red[2] + red[3]) * (1.0f / H);
  float d = y - mean, q = d * d;
  for (int off = 32; off; off >>= 1) q += __shfl_down(q, off);
  if (lane == 0) red[4 + wv] = q;
  __syncthreads();
  float var = (red[4] + red[5] + red[6] + red[7]) * (1.0f / H);
  float h = d / sqrtf(var + 1e-5f) * ln_g[tid] + ln_b[tid];
  h = h > 0.f ? h : 0.01f * h;
  hc[tid] = h;
  __syncthreads();
  float am = 0.f, ae = 0.f;
  for (int cin = 0; cin < H; ++cin) {
    float hv = hc[cin];
    float p0 = post_w[(0 * H + cin) * H + tid];
    float p1 = post_w[(1 * H + cin) * H + tid];
    float p2 = post_w[(2 * H + cin) * H + tid];
    am += (p0 + p1 + p2) * hv;
    ae += (p0 + p1) * hv;
  }
  zm[tid] = am + post_b[tid];
  ze[tid] = ae + post_b[tid];
  __syncthreads();
  if (tid < NOTE_CLS) {
    float sm = 0.f, se = 0.f;
    for (int c = 0; c < H; ++c) {
      float w = w_pitch[c * NOTE_CLS + tid];
      sm += zm[c] * w; se += ze[c] * w;
    }
    lm[tid] = sm + b_pitch[tid]; le[tid] = se + b_pitch[tid];
    lmid[tid] = lm[tid]; ledge[tid] = le[tid];
  }
  __syncthreads();
  if (tid == 0) {
    int bi = 0; float bv = lm[0];
    for (int p = 1; p < NOTE_CLS; ++p) if (lm[p] > bv) { bv = lm[p]; bi = p; }
    preds[0] = (bi > NOTE_NUM || bi < NOTE_START) ? 0 : bi;
    bi = 0; bv = le[0];
    for (int p = 1; p < NOTE_CLS; ++p) if (le[p] > bv) { bv = le[p]; bi = p; }
    preds[1] = (bi > NOTE_NUM || bi < NOTE_START) ? 0 : bi;
  }
}

// ---------------- Kernel 4: segment weighted means ---------------------------
__global__ __launch_bounds__(64) void k_seg(
    const float* __restrict__ feat, const float* __restrict__ amean,
    const int* __restrict__ seg_start, const int* __restrict__ note_len,
    float* __restrict__ agg)
{
  int blk = blockIdx.x;
  int b = blk / NSEG, n = blk - b * NSEG;
  int len = note_len[b];
  int lane = threadIdx.x;
  float4* o4 = (float4*)(agg + ((size_t)b * NSEG + n) * H);
  if (n >= len) {
    if (n < len + 40) o4[lane] = make_float4(0.f, 0.f, 0.f, 0.f);
    return;
  }
  int s = seg_start[b * (T + 2) + n];
  int e = seg_start[b * (T + 2) + n + 1];
  float4 acc = make_float4(0.f, 0.f, 0.f, 0.f);
  float dsum = 0.f;
  for (int t = s; t < e; ++t) {
    float am = amean[(size_t)b * T + t];
    float4 f = ((const float4*)(feat + ((size_t)b * T + t) * H))[lane];
    acc.x += am * f.x; acc.y += am * f.y; acc.z += am * f.z; acc.w += am * f.w;
    dsum += am;
  }
  float dn = dsum + 1e-5f;
  acc.x /= dn; acc.y /= dn; acc.z /= dn; acc.w /= dn;
  o4[lane] = acc;
}

// ---------------- Kernel 5 helpers (PG = position half, TM=9/8, static idx) --
template<int PG>
__device__ __forceinline__ void conv1_t(
    const float* __restrict__ cw, const float* __restrict__ cb, int cout,
    const float (*xs)[XSTR], float (&acc)[9], float (*rs)[4], float (*rq)[4],
    int lane, int wv4)
{
  constexpr int XB = PG ? 8 : 0;
  constexpr int S  = PG ? 1 : 0;
  #pragma unroll
  for (int j = 0; j < 9; ++j) acc[j] = 0.f;
  #pragma unroll 2
  for (int cin = 0; cin < H; ++cin) {
    float w0 = cw[cin * H + cout];
    float w1 = cw[(H + cin) * H + cout];
    float w2 = cw[(2 * H + cin) * H + cout];
    float4 a = *(const float4*)&xs[cin][XB];
    float4 bq = *(const float4*)&xs[cin][XB + 4];
    float4 c = *(const float4*)&xs[cin][XB + 8];
    float L[12] = { a.x, a.y, a.z, a.w, bq.x, bq.y, bq.z, bq.w, c.x, c.y, c.z, c.w };
    #pragma unroll
    for (int j = 0; j < 9; ++j)
      acc[j] += w0 * L[j + S] + w1 * L[j + S + 1] + w2 * L[j + S + 2];
  }
  float cbv = cb[cout];
  #pragma unroll
  for (int j = 0; j < 9; ++j) {
    acc[j] += cbv;
    float s = acc[j], q = acc[j] * acc[j];
    for (int off = 32; off; off >>= 1) { s += __shfl_down(s, off); q += __shfl_down(q, off); }
    if (lane == 0) { rs[PG * 9 + j][wv4] = s; rq[PG * 9 + j][wv4] = q; }
  }
}

template<int PG>
__device__ __forceinline__ void u_t(
    const float* __restrict__ g_, const float* __restrict__ b_, int cout, int t0,
    const float (*xs)[XSTR], float (*us)[XSTR], const float (&acc)[9],
    const float* sm, const float* sr)
{
  float g = g_[cout], bb = b_[cout];
  #pragma unroll
  for (int j = 0; j < 9; ++j) {
    int m = PG * 9 + j;
    int p = t0 - 1 + m;
    float h = (acc[j] - sm[m]) * sr[m] * g + bb;
    h = h > 0.f ? h : 0.01f * h;
    us[cout][m] = (p >= 0 && p < NPOS) ? xs[cout][m + 1] + h : 0.f;
  }
  if (PG == 1) { us[cout][18] = 0.f; us[cout][19] = 0.f; }
}

template<int PG>
__device__ __forceinline__ void conv2_t(
    const float* __restrict__ pw, const float* __restrict__ pb, int cout,
    const float (*us)[XSTR], float* zt)
{
  constexpr int XB2 = PG ? 8 : 0;
  float a2[8];
  #pragma unroll
  for (int j = 0; j < 8; ++j) a2[j] = 0.f;
  #pragma unroll 2
  for (int cin = 0; cin < H; ++cin) {
    float w0 = pw[cin * H + cout];
    float w1 = pw[(H + cin) * H + cout];
    float w2 = pw[(2 * H + cin) * H + cout];
    float4 a = *(const float4*)&us[cin][XB2];
    float4 bq = *(const float4*)&us[cin][XB2 + 4];
    float4 c = *(const float4*)&us[cin][XB2 + 8];
    float L[12] = { a.x, a.y, a.z, a.w, bq.x, bq.y, bq.z, bq.w, c.x, c.y, c.z, c.w };
    #pragma unroll
    for (int j = 0; j < 8; ++j)
      a2[j] += w0 * L[j] + w1 * L[j + 1] + w2 * L[j + 2];
  }
  float pbv = pb[cout];
  #pragma unroll
  for (int j = 0; j < 8; ++j) zt[(PG * 8 + j) * ZSTR + cout] = a2[j] + pbv;
}

// ---------------- Kernel 5: conv -> LN -> leaky -> conv -> pitch -> argmax ---
__global__ __launch_bounds__(512) void k_conv_full(
    const float* __restrict__ agg,
    const float* __restrict__ conv_w, const float* __restrict__ conv_b,
    const float* __restrict__ ln_g, const float* __restrict__ ln_b,
    const float* __restrict__ post_w, const float* __restrict__ post_b,
    const float* __restrict__ w_pitch, const float* __restrict__ b_pitch,
    const int* __restrict__ note_len,
    float* __restrict__ out3, float* __restrict__ out4)
{
  int blk = blockIdx.x;
  int b = blk / NT2, tile = blk - b * NT2;
  int t0 = tile * T2;
  int len = note_len[b];
  if (t0 > len + 2) return;                      // tail kernel handles the rest

  __shared__ float xs[H][XSTR];                  // agg rows (20 used)
  __shared__ float us[H][XSTR];                  // u rows (18 used + 2 zero)
  __shared__ float zt[T2 * ZSTR];                // z transposed [n][cout]
  __shared__ float rs_[18][4], rq_[18][4];
  __shared__ float stat_mean[18], stat_rstd[18];
  __shared__ float pvs[T2][26];
  __shared__ int   pis[T2][26];

  int tid = threadIdx.x;
  int cout = tid & 255;
  int pg = tid >> 8;                             // 0..1, wave-uniform
  int lane = tid & 63;
  int wv4 = (tid >> 6) & 3;
  const float* aggb = agg + (size_t)b * NSEG * H;

  #pragma unroll
  for (int i = 0; i < 10; ++i) {
    int r = pg * 10 + i;
    int p = t0 - 2 + r;
    float v = 0.f;
    if (p >= 0 && p < NSEG) v = aggb[(size_t)p * H + cout];
    xs[cout][r] = v;
  }
  __syncthreads();

  float acc[9];
  if (pg == 0) conv1_t<0>(conv_w, conv_b, cout, xs, acc, rs_, rq_, lane, wv4);
  else         conv1_t<1>(conv_w, conv_b, cout, xs, acc, rs_, rq_, lane, wv4);
  __syncthreads();

  if (tid < 18) {
    float S = rs_[tid][0] + rs_[tid][1] + rs_[tid][2] + rs_[tid][3];
    float Q = rq_[tid][0] + rq_[tid][1] + rq_[tid][2] + rq_[tid][3];
    float mean = S * (1.0f / H);
    float var = Q * (1.0f / H) - mean * mean;
    if (var < 0.f) var = 0.f;
    stat_mean[tid] = mean;
    stat_rstd[tid] = 1.0f / sqrtf(var + 1e-5f);
  }
  __syncthreads();

  if (pg == 0) u_t<0>(ln_g, ln_b, cout, t0, xs, us, acc, stat_mean, stat_rstd);
  else         u_t<1>(ln_g, ln_b, cout, t0, xs, us, acc, stat_mean, stat_rstd);
  __syncthreads();

  if (pg == 0) conv2_t<0>(post_w, post_b, cout, us, zt);
  else         conv2_t<1>(post_w, post_b, cout, us, zt);
  __syncthreads();

  // pitch head: 208 threads = 8 n-groups x 26 class-quads; 2 positions each
  if (tid < 208) {
    int n8 = tid / 26, c26 = tid - n8 * 26;
    float4 a0 = make_float4(0.f, 0.f, 0.f, 0.f), a1 = a0;
    const float* z0 = &zt[n8 * ZSTR];
    const float* z1 = &zt[(n8 + 8) * ZSTR];
    #pragma unroll 2
    for (int cin = 0; cin < H; ++cin) {
      float4 w4 = *(const float4*)&w_pitch[cin * NOTE_CLS + 4 * c26];
      float zv0 = z0[cin], zv1 = z1[cin];
      a0.x += zv0 * w4.x; a0.y += zv0 * w4.y; a0.z += zv0 * w4.z; a0.w += zv0 * w4.w;
      a1.x += zv1 * w4.x; a1.y += zv1 * w4.y; a1.z += zv1 * w4.z; a1.w += zv1 * w4.w;
    }
    float4 bp = *(const float4*)&b_pitch[4 * c26];
    a0.x += bp.x; a0.y += bp.y; a0.z += bp.z; a0.w += bp.w;
    a1.x += bp.x; a1.y += bp.y; a1.z += bp.z; a1.w += bp.w;
    #pragma unroll
    for (int r = 0; r < 2; ++r) {
      int n = n8 + 8 * r;
      float4 o = r ? a1 : a0;
      if (t0 + n < NPOS)
        *(float4*)&out3[((size_t)b * NPOS + (t0 + n)) * NOTE_CLS + 4 * c26] = o;
      float bv = o.x; int bi = 4 * c26;
      if (o.y > bv) { bv = o.y; bi = 4 * c26 + 1; }
      if (o.z > bv) { bv = o.z; bi = 4 * c26 + 2; }
      if (o.w > bv) { bv = o.w; bi = 4 * c26 + 3; }
      pvs[n][c26] = bv; pis[n][c26] = bi;
    }
  }
  __syncthreads();
  if (tid < T2 && t0 + tid < NPOS) {
    float bv = pvs[tid][0]; int bi = pis[tid][0];
    #pragma unroll 1
    for (int k = 1; k < 26; ++k)
      if (pvs[tid][k] > bv) { bv = pvs[tid][k]; bi = pis[tid][k]; }
    int pred = (bi > NOTE_NUM || bi < NOTE_START) ? 0 : bi;
    out4[(size_t)b * NPOS + t0 + tid] = (float)pred;
  }
}

// ---------------- Kernel 6: constant tail broadcast (16-tiles) ---------------
__global__ __launch_bounds__(256) void k_tail(
    const float* __restrict__ lmid, const float* __restrict__ ledge,
    const int* __restrict__ preds, const int* __restrict__ note_len,
    float* __restrict__ out3, float* __restrict__ out4)
{
  int blk = blockIdx.x;
  int b = blk / NT2, tile = blk - b * NT2;
  int t0 = tile * T2;
  int len = note_len[b];
  if (t0 <= len + 2) return;                    // handled by k_conv_full
  __shared__ float lm[NOTE_CLS], le[NOTE_CLS];
  int tid = threadIdx.x;
  if (tid < NOTE_CLS) { lm[tid] = lmid[tid]; le[tid] = ledge[tid]; }
  __syncthreads();
  int pm = preds[0], pe = preds[1];
  for (int i = tid; i < T2 * NOTE_CLS; i += 256) {
    int dn = i / NOTE_CLS;
    int n = t0 + dn, p = i - dn * NOTE_CLS;
    if (n >= NPOS) continue;
    out3[((size_t)b * NPOS + n) * NOTE_CLS + p] = (n == NPOS - 1) ? le[p] : lm[p];
  }
  if (tid < T2) {
    int n = t0 + tid;
    if (n < NPOS) out4[(size_t)b * NPOS + n] = (float)((n == NPOS - 1) ? pe : pm);
  }
}

// ---------------- launcher ---------------------------------------------------
extern "C" void kernel_launch(void* const* d_in, const int* in_sizes, int n_in,
                              void* d_out, int out_size, void* d_ws, size_t ws_size,
                              hipStream_t stream) {
  (void)in_sizes; (void)n_in; (void)out_size; (void)ws_size;
  const float* feat    = (const float*)d_in[0];
  const int*   nonpad  = (const int*)d_in[1];
  const float* w_bd    = (const float*)d_in[2];
  const float* b_bd    = (const float*)d_in[3];
  const float* w_attn  = (const float*)d_in[4];
  const float* b_attn  = (const float*)d_in[5];
  const float* conv_w  = (const float*)d_in[6];
  const float* conv_b  = (const float*)d_in[7];
  const float* ln_g    = (const float*)d_in[8];
  const float* ln_b    = (const float*)d_in[9];
  const float* post_w  = (const float*)d_in[10];
  const float* post_b  = (const float*)d_in[11];
  const float* w_pitch = (const float*)d_in[12];
  const float* b_pitch = (const float*)d_in[13];

  float* out  = (float*)d_out;
  float* out0 = out;                                  // [B,T] note_bd_logits
  float* out1 = out + (size_t)B * T;                  // [B,T] note_bd
  float* out2 = out + 2ull * B * T;                   // [B]   note_lengths
  float* out3 = out2 + B;                             // [B,NPOS,104] note_logits
  float* out4 = out3 + (size_t)B * NPOS * NOTE_CLS;   // [B,NPOS] note_pred

  char* ws = (char*)d_ws;
  double* dlog  = (double*)(ws + 0);                  // 768000 B
  float*  amean = (float*)(ws + 768000);              // 384000 B
  int*    segst = (int*)(ws + 1152000);               // 384128 B
  int*    nlen  = (int*)(ws + 1536128);               // 64 B
  float*  lmid  = (float*)(ws + 1536192);             // 416 B
  float*  ledge = (float*)(ws + 1536608);             // 416 B
  int*    preds = (int*)(ws + 1537024);               // 8 B
  float*  agg   = (float*)(ws + 1537536);             // 16*1024*256*4 = 16.78 MB

  k_dots<<<(B * T) / 4, 256, 0, stream>>>(feat, w_bd, b_bd, w_attn, b_attn, out0, dlog, amean);
  k_regulate<<<B, 256, 0, stream>>>(dlog, nonpad, out1, out2, segst, nlen);
  k_consts<<<1, 256, 0, stream>>>(conv_b, ln_g, ln_b, post_w, post_b, w_pitch, b_pitch, lmid, ledge, preds);
  k_seg<<<B * NSEG, 64, 0, stream>>>(feat, amean, segst, nlen, agg);
  k_conv_full<<<B * NT2, 512, 0, stream>>>(agg, conv_w, conv_b, ln_g, ln_b, post_w, post_b,
                                           w_pitch, b_pitch, nlen, out3, out4);
  k_tail<<<B * NT2, 256, 0, stream>>>(lmid, ledge, preds, nlen, out3, out4);
}